// Round 1
// baseline (4568.747 us; speedup 1.0000x reference)
//
#include <hip/hip_runtime.h>
#include <math.h>

#define FW_ 180
#define FH_ 180
#define HW_ (FW_*FH_)
#define CIN_ 128
#define BB_ 4
#define MM_ 500

// d_out segment offsets (floats), in reference return order
#define HM_OFF   0
#define REG_OFF  (BB_*2*HW_)                   // 259200
#define HEAT_OFF (REG_OFF + BB_*9*HW_)         // 1425600
#define RB_OFF   (HEAT_OFF + BB_*2*HW_)        // 1684800
#define IND_OFF  (RB_OFF + BB_*MM_*5*8)        // 1764800
#define MSK_OFF  (IND_OFF + BB_*MM_*5)         // 1774800
#define HMM_OFF  (MSK_OFF + BB_*MM_*5)         // 1784800

// ---------------------------------------------------------------------------
// conv 3x3 SAME, C_in=128 -> C_out=128, fused BN + ReLU.
// Thread tile: 4 out-channels x 1 row x 4 cols. 18 input loads + 36 weight
// loads per c_in iter feed 144 FMAs.
// ---------------------------------------------------------------------------
__global__ __launch_bounds__(256) void k_conv128(
    const float* __restrict__ in, const float* __restrict__ wgt,
    const float* __restrict__ gg, const float* __restrict__ bb,
    const float* __restrict__ mm, const float* __restrict__ vv,
    float* __restrict__ out)
{
    int tid = blockIdx.x * 256 + threadIdx.x;
    int wg = tid % 45;
    int t  = tid / 45;
    int h  = t % 180; t /= 180;
    int cog = t & 31;
    int b   = t >> 5;
    int w0 = wg * 4, co0 = cog * 4;

    const float* inb = in + (size_t)b * CIN_ * HW_;
    const float* wp  = wgt + (size_t)co0 * CIN_ * 9;

    float acc[4][4] = {};
    bool rok0 = (h >= 1), rok2 = (h <= 178);
    bool c0ok = (w0 >= 1), c5ok = (w0 + 4 < FW_);

    for (int ci = 0; ci < CIN_; ++ci) {
        float xv[3][6];
#pragma unroll
        for (int r = 0; r < 3; ++r) {
            bool rok = (r == 1) ? true : (r == 0 ? rok0 : rok2);
            const float* rp = inb + (size_t)ci * HW_ + (h + r - 1) * FW_ + w0;
            xv[r][0] = (rok && c0ok) ? rp[-1] : 0.f;
#pragma unroll
            for (int c = 1; c < 5; ++c) xv[r][c] = rok ? rp[c - 1] : 0.f;
            xv[r][5] = (rok && c5ok) ? rp[4] : 0.f;
        }
#pragma unroll
        for (int j = 0; j < 4; ++j) {
            const float* wq = wp + ((size_t)j * CIN_ + ci) * 9;
            float wv[9];
#pragma unroll
            for (int k = 0; k < 9; ++k) wv[k] = wq[k];
#pragma unroll
            for (int r = 0; r < 3; ++r)
#pragma unroll
                for (int kw = 0; kw < 3; ++kw)
#pragma unroll
                    for (int c = 0; c < 4; ++c)
                        acc[j][c] = fmaf(wv[r * 3 + kw], xv[r][c + kw], acc[j][c]);
        }
    }
#pragma unroll
    for (int j = 0; j < 4; ++j) {
        int co = co0 + j;
        float sc = gg[co] / sqrtf(vv[co] + 1e-5f);
        float sh = bb[co] - mm[co] * sc;
        float* op = out + ((size_t)(b * CIN_ + co) * FH_ + h) * FW_ + w0;
#pragma unroll
        for (int c = 0; c < 4; ++c) {
            float y = acc[j][c] * sc + sh;
            op[c] = y > 0.f ? y : 0.f;
        }
    }
}

// ---------------------------------------------------------------------------
// head: hm (2ch, +bias) and reg (9ch, +bias) from f2, written to d_out.
// Thread tile: 11 out-channels x 4 cols.
// ---------------------------------------------------------------------------
__global__ __launch_bounds__(256) void k_head(
    const float* __restrict__ in,
    const float* __restrict__ hw, const float* __restrict__ hb,
    const float* __restrict__ rw, const float* __restrict__ rb,
    float* __restrict__ out)
{
    int tid = blockIdx.x * 256 + threadIdx.x;
    if (tid >= BB_ * 180 * 45) return;
    int wg = tid % 45;
    int t  = tid / 45;
    int h  = t % 180;
    int b  = t / 180;
    int w0 = wg * 4;

    const float* inb = in + (size_t)b * CIN_ * HW_;
    float acc[11][4] = {};
    bool rok0 = (h >= 1), rok2 = (h <= 178);
    bool c0ok = (w0 >= 1), c5ok = (w0 + 4 < FW_);

    for (int ci = 0; ci < CIN_; ++ci) {
        float xv[3][6];
#pragma unroll
        for (int r = 0; r < 3; ++r) {
            bool rok = (r == 1) ? true : (r == 0 ? rok0 : rok2);
            const float* rp = inb + (size_t)ci * HW_ + (h + r - 1) * FW_ + w0;
            xv[r][0] = (rok && c0ok) ? rp[-1] : 0.f;
#pragma unroll
            for (int c = 1; c < 5; ++c) xv[r][c] = rok ? rp[c - 1] : 0.f;
            xv[r][5] = (rok && c5ok) ? rp[4] : 0.f;
        }
#pragma unroll
        for (int co = 0; co < 11; ++co) {
            const float* wq = (co < 2) ? (hw + ((size_t)co * CIN_ + ci) * 9)
                                       : (rw + ((size_t)(co - 2) * CIN_ + ci) * 9);
            float wv[9];
#pragma unroll
            for (int k = 0; k < 9; ++k) wv[k] = wq[k];
#pragma unroll
            for (int r = 0; r < 3; ++r)
#pragma unroll
                for (int kw = 0; kw < 3; ++kw)
#pragma unroll
                    for (int c = 0; c < 4; ++c)
                        acc[co][c] = fmaf(wv[r * 3 + kw], xv[r][c + kw], acc[co][c]);
        }
    }
#pragma unroll
    for (int co = 0; co < 11; ++co) {
        float bias = (co < 2) ? hb[co] : rb[co - 2];
        float* op = (co < 2)
            ? (out + HM_OFF  + ((size_t)(b * 2 + co) * FH_ + h) * FW_ + w0)
            : (out + REG_OFF + ((size_t)(b * 9 + (co - 2)) * FH_ + h) * FW_ + w0);
#pragma unroll
        for (int c = 0; c < 4; ++c) op[c] = acc[co][c] + bias;
    }
}

// ---------------------------------------------------------------------------
// targets
// ---------------------------------------------------------------------------
__global__ void k_zero_heat(float* __restrict__ out)
{
    int i = blockIdx.x * 256 + threadIdx.x;
    if (i < BB_ * 2 * HW_) out[HEAT_OFF + i] = 0.f;
}

__global__ void k_objects(const float* __restrict__ gt, float* __restrict__ out)
{
    int ob = blockIdx.x;              // 0 .. B*M-1
    int b = ob / MM_, m = ob % MM_;
    const float* gp = gt + (size_t)ob * 8;
    float x = gp[0], y = gp[1], z = gp[2];
    float dx = gp[3], dy = gp[4], dz = gp[5], ry = gp[6];
    int cls = (int)gp[7];

    float coord_x = fminf(fmaxf((x + 54.f) / 0.075f / 8.f, 0.f), 179.5f);
    float coord_y = fminf(fmaxf((y + 54.f) / 0.075f / 8.f, 0.f), 179.5f);
    int cxi = (int)coord_x, cyi = (int)coord_y;
    float dxp = dx / 0.075f / 8.f;
    float dyp = dy / 0.075f / 8.f;

    // gaussian_radius(height=dxp, width=dyp, 0.1)
    float hgt = dxp, wid = dyp, mo = 0.1f;
    float b1 = hgt + wid, c1 = wid * hgt * (1.f - mo) / (1.f + mo);
    float r1 = (b1 + sqrtf(fmaxf(b1 * b1 - 4.f * c1, 0.f))) * 0.5f;
    float b2 = 2.f * (hgt + wid), c2 = (1.f - mo) * wid * hgt;
    float r2 = (b2 + sqrtf(fmaxf(b2 * b2 - 16.f * c2, 0.f))) * 0.5f;
    float a3 = 4.f * mo, b3 = -2.f * mo * (hgt + wid), c3 = (mo - 1.f) * wid * hgt;
    float r3 = (b3 + sqrtf(fmaxf(b3 * b3 - 4.f * a3 * c3, 0.f))) / (2.f * a3);
    int radius = max((int)fminf(fminf(r1, r2), r3), 2);

    bool valid = (dxp > 0.f) && (dyp > 0.f);
    bool pos = valid && (cls >= 1);

    if (threadIdx.x == 0) {
        float m0 = valid ? (cls >= 1 ? 1.f : -1.f) : 0.f;
        bool w_cond = (0.075f * 8.f) > dy / 4.f;
        bool l_cond = (0.075f * 8.f) > dx / 4.f;
        bool s1 = valid && !w_cond && (cxi - 1 >= 0);
        bool s2 = valid && !w_cond && (cxi + 1 < FW_);
        bool s3 = valid && !l_cond && (cyi - 1 >= 0);
        bool s4 = valid && !l_cond && (cyi + 1 < FH_);
        int base_ind = cyi * FW_ + cxi;

        float* indp = out + IND_OFF + (size_t)b * MM_ * 5 + m * 5;
        float* mskp = out + MSK_OFF + (size_t)b * MM_ * 5 + m * 5;
        indp[0] = valid ? (float)base_ind : 0.f;
        indp[1] = s1 ? (float)(base_ind - 1) : 0.f;
        indp[2] = s2 ? (float)(base_ind + 1) : 0.f;
        indp[3] = s3 ? (float)(base_ind - FW_) : 0.f;
        indp[4] = s4 ? (float)(base_ind + FW_) : 0.f;
        mskp[0] = m0;
        mskp[1] = s1 ? m0 : 0.f;
        mskp[2] = s2 ? m0 : 0.f;
        mskp[3] = s3 ? m0 : 0.f;
        mskp[4] = s4 ? m0 : 0.f;

        float offx = coord_x - (float)cxi;
        float offy = coord_y - (float)cyi;
        float bse[8] = { offx, offy, z,
                         logf(fmaxf(dx, 1e-8f)), logf(fmaxf(dy, 1e-8f)),
                         logf(fmaxf(dz, 1e-8f)), cosf(ry), sinf(ry) };
        float vm = valid ? 1.f : 0.f;
        float* rbp = out + RB_OFF + ((size_t)b * MM_ + m) * 5 * 8;
#pragma unroll
        for (int s = 0; s < 5; ++s) {
            float t0 = bse[0], t1 = bse[1];
            if (s == 1) t0 += s1 ? 1.f : 0.f;
            if (s == 2) t0 -= s2 ? 1.f : 0.f;
            if (s == 3) t1 += s3 ? 1.f : 0.f;
            if (s == 4) t1 -= s4 ? 1.f : 0.f;
            rbp[s * 8 + 0] = t0 * vm;
            rbp[s * 8 + 1] = t1 * vm;
#pragma unroll
            for (int k = 2; k < 8; ++k) rbp[s * 8 + k] = bse[k] * vm;
        }
    }

    if (pos) {
        float sigma = (2.f * (float)radius + 1.f) / 6.f;
        float inv2s2 = 1.f / (2.f * sigma * sigma);
        int x0 = max(cxi - radius, 0), x1 = min(cxi + radius, FW_ - 1);
        int y0 = max(cyi - radius, 0), y1 = min(cyi + radius, FH_ - 1);
        int wdt = x1 - x0 + 1, tot = wdt * (y1 - y0 + 1);
        float* hp = out + HEAT_OFF + (size_t)(b * 2 + (cls - 1)) * HW_;
        for (int i = threadIdx.x; i < tot; i += blockDim.x) {
            int yy = y0 + i / wdt, xx = x0 + i % wdt;
            float ddy = (float)(yy - cyi), ddx = (float)(xx - cxi);
            float gvl = expf(-(ddy * ddy + ddx * ddx) * inv2s2);
            atomicMax((int*)(hp + yy * FW_ + xx), __float_as_int(gvl));
        }
    }
}

__global__ void k_hm_mask(float* __restrict__ out)
{
    int i = blockIdx.x * 256 + threadIdx.x;
    if (i < BB_ * 2 * HW_) {
        float v = out[HEAT_OFF + i];
        out[HMM_OFF + i] = v > 0.f ? 1.f : 0.f;
    }
}

// ---------------------------------------------------------------------------
extern "C" void kernel_launch(void* const* d_in, const int* in_sizes, int n_in,
                              void* d_out, int out_size, void* d_ws, size_t ws_size,
                              hipStream_t stream)
{
    const float* x  = (const float*)d_in[0];
    const float* gt = (const float*)d_in[1];
    const float* w1 = (const float*)d_in[2];
    const float* g1 = (const float*)d_in[3];
    const float* b1 = (const float*)d_in[4];
    const float* m1 = (const float*)d_in[5];
    const float* v1 = (const float*)d_in[6];
    const float* w2 = (const float*)d_in[7];
    const float* g2 = (const float*)d_in[8];
    const float* b2 = (const float*)d_in[9];
    const float* m2 = (const float*)d_in[10];
    const float* v2 = (const float*)d_in[11];
    const float* hw = (const float*)d_in[12];
    const float* hb = (const float*)d_in[13];
    const float* rw = (const float*)d_in[14];
    const float* rb = (const float*)d_in[15];
    float* out = (float*)d_out;

    float* f1 = (float*)d_ws;                       // 4*128*180*180 floats
    float* f2 = f1 + (size_t)BB_ * CIN_ * HW_;      // second intermediate

    // conv1 + bn1 + relu
    k_conv128<<<4050, 256, 0, stream>>>(x, w1, g1, b1, m1, v1, f1);
    // conv2 + bn2 + relu
    k_conv128<<<4050, 256, 0, stream>>>(f1, w2, g2, b2, m2, v2, f2);
    // hm + reg heads
    k_head<<<(BB_ * 180 * 45 + 255) / 256, 256, 0, stream>>>(f2, hw, hb, rw, rb, out);
    // targets
    k_zero_heat<<<(BB_ * 2 * HW_ + 255) / 256, 256, 0, stream>>>(out);
    k_objects<<<BB_ * MM_, 64, 0, stream>>>(gt, out);
    k_hm_mask<<<(BB_ * 2 * HW_ + 255) / 256, 256, 0, stream>>>(out);
}

// Round 2
// 1440.212 us; speedup vs baseline: 3.1723x; 3.1723x over previous
//
#include <hip/hip_runtime.h>
#include <math.h>

#define FW_ 180
#define FH_ 180
#define HW_ (FW_*FH_)
#define CIN_ 128
#define BB_ 4
#define MM_ 500
#define CK 8

// d_out segment offsets (floats), in reference return order
#define HM_OFF   0
#define REG_OFF  (BB_*2*HW_)                   // 259200
#define HEAT_OFF (REG_OFF + BB_*9*HW_)         // 1425600
#define RB_OFF   (HEAT_OFF + BB_*2*HW_)        // 1684800
#define IND_OFF  (RB_OFF + BB_*MM_*5*8)        // 1764800
#define MSK_OFF  (IND_OFF + BB_*MM_*5)         // 1774800
#define HMM_OFF  (MSK_OFF + BB_*MM_*5)         // 1784800

// ---------------------------------------------------------------------------
// weight transpose: w[co][ci][3][3] -> wT[(ci*9+k)][co]  (co fastest)
// ---------------------------------------------------------------------------
__global__ void k_prep_wT(const float* __restrict__ w, float* __restrict__ wT)
{
    int i = blockIdx.x * 256 + threadIdx.x;
    if (i >= CIN_ * CIN_ * 9) return;
    int co = i & 127;
    int jk = i >> 7;                 // ci*9 + k
    int ci = jk / 9, k = jk - 9 * ci;
    wT[i] = w[((size_t)co * CIN_ + ci) * 9 + k];
}

// head weights: hm(2co) + reg(9co) -> wTh[(ci*9+k)][co12pad]
__global__ void k_prep_wTh(const float* __restrict__ hw, const float* __restrict__ rw,
                           float* __restrict__ wTh)
{
    int i = blockIdx.x * 256 + threadIdx.x;
    if (i >= CIN_ * 9 * 12) return;
    int co = i % 12;
    int jk = i / 12;
    int ci = jk / 9, k = jk - 9 * ci;
    float v = 0.f;
    if (co < 2)       v = hw[((size_t)co * CIN_ + ci) * 9 + k];
    else if (co < 11) v = rw[((size_t)(co - 2) * CIN_ + ci) * 9 + k];
    wTh[i] = v;
}

// ---------------------------------------------------------------------------
// conv 3x3 SAME 128->128 + BN + ReLU, LDS-tiled.
// Block: 64 co x 16x16 px. Thread: 8 co x (2 rows x 4 cols).
// ---------------------------------------------------------------------------
__global__ __launch_bounds__(256, 3) void k_conv_t(
    const float* __restrict__ in, const float* __restrict__ wT,
    const float* __restrict__ gg, const float* __restrict__ bb,
    const float* __restrict__ mm, const float* __restrict__ vv,
    float* __restrict__ out)
{
    __shared__ float lin[CK * 360];      // [ci][18 rows][20 cols pad]
    __shared__ float lw[72 * 64];        // [ci*9+k][co64]

    int tid = threadIdx.x;
    int sp  = blockIdx.x;                // 0..143
    int bx  = sp % 12, by = sp / 12;
    int cot = blockIdx.y;                // 0..1
    int b   = blockIdx.z;
    int cog = tid & 7, pxg = tid >> 3;
    int pxr = pxg >> 2, pxc = pxg & 3;
    int r0 = 2 * pxr, c0 = 4 * pxc;
    int row_base = by * 16, col_base = bx * 16;
    int co_t = cot * 64 + cog * 8;

    const float* inb = in + (size_t)b * CIN_ * HW_;

    float sc[8], sh[8];
#pragma unroll
    for (int j = 0; j < 8; ++j) {
        float s = gg[co_t + j] / sqrtf(vv[co_t + j] + 1e-5f);
        sc[j] = s;
        sh[j] = bb[co_t + j] - mm[co_t + j] * s;
    }

    float acc[8][8] = {};                // [co_j][r*4+c]

    for (int ch = 0; ch < CIN_ / CK; ++ch) {
        int ci0 = ch * CK;
        __syncthreads();
        // stage input patch (zero-padded borders)
        for (int idx = tid; idx < CK * 18 * 18; idx += 256) {
            int ci = idx / 324;
            int rem = idx - ci * 324;
            int r = rem / 18, c = rem - r * 18;
            int gr = row_base - 1 + r, gc = col_base - 1 + c;
            float v = 0.f;
            if ((unsigned)gr < 180u && (unsigned)gc < 180u)
                v = inb[(size_t)(ci0 + ci) * HW_ + gr * FW_ + gc];
            lin[ci * 360 + r * 20 + c] = v;
        }
        // stage weights: contiguous rows of wT, float4
        for (int idx = tid; idx < 72 * 16; idx += 256) {
            int j = idx >> 4, q = idx & 15;
            float4 w4 = *(const float4*)&wT[(size_t)(ci0 * 9 + j) * CIN_ + cot * 64 + q * 4];
            *(float4*)&lw[j * 64 + q * 4] = w4;
        }
        __syncthreads();

#pragma unroll 1
        for (int ci = 0; ci < CK; ++ci) {
            float xv[4][6];
#pragma unroll
            for (int rr = 0; rr < 4; ++rr) {
                const float* lp = &lin[ci * 360 + (r0 + rr) * 20 + c0];
                float4 a = *(const float4*)lp;
                xv[rr][0] = a.x; xv[rr][1] = a.y; xv[rr][2] = a.z; xv[rr][3] = a.w;
                xv[rr][4] = lp[4]; xv[rr][5] = lp[5];
            }
#pragma unroll
            for (int k = 0; k < 9; ++k) {
                int kr = k / 3, kc = k % 3;
                const float* wp = &lw[(ci * 9 + k) * 64 + cog * 8];
                float4 wa = *(const float4*)wp;
                float4 wb = *(const float4*)(wp + 4);
                float wv[8] = {wa.x, wa.y, wa.z, wa.w, wb.x, wb.y, wb.z, wb.w};
#pragma unroll
                for (int j = 0; j < 8; ++j)
#pragma unroll
                    for (int r = 0; r < 2; ++r)
#pragma unroll
                        for (int c = 0; c < 4; ++c)
                            acc[j][r * 4 + c] = fmaf(wv[j], xv[r + kr][c + kc], acc[j][r * 4 + c]);
            }
        }
    }

    int gc0 = col_base + c0;
    if (gc0 < FW_) {
#pragma unroll
        for (int j = 0; j < 8; ++j) {
#pragma unroll
            for (int r = 0; r < 2; ++r) {
                int gr = row_base + r0 + r;
                if (gr < FH_) {
                    float4 o;
                    o.x = fmaxf(fmaf(acc[j][r * 4 + 0], sc[j], sh[j]), 0.f);
                    o.y = fmaxf(fmaf(acc[j][r * 4 + 1], sc[j], sh[j]), 0.f);
                    o.z = fmaxf(fmaf(acc[j][r * 4 + 2], sc[j], sh[j]), 0.f);
                    o.w = fmaxf(fmaf(acc[j][r * 4 + 3], sc[j], sh[j]), 0.f);
                    *(float4*)&out[((size_t)(b * CIN_ + co_t + j) * FH_ + gr) * FW_ + gc0] = o;
                }
            }
        }
    }
}

// ---------------------------------------------------------------------------
// head: 11 outputs (2 hm + 9 reg), LDS-tiled.
// Block: 128 thr, tile 32 cols x 16 rows. Thread: 11 co x (2x2) px.
// ---------------------------------------------------------------------------
__global__ __launch_bounds__(128, 4) void k_head_t(
    const float* __restrict__ in, const float* __restrict__ wTh,
    const float* __restrict__ hb, const float* __restrict__ rb,
    float* __restrict__ out)
{
    __shared__ float lin[CK * 18 * 36];  // [ci][18 rows][36 cols pad(34 used)]
    __shared__ float lw[72 * 12];        // [ci*9+k][co12]

    int tid = threadIdx.x;
    int sp = blockIdx.x;                 // 0..71
    int bx = sp % 6, by = sp / 6;        // 6 x 12 tiles
    int b  = blockIdx.y;
    int cg = tid & 15, rg = tid >> 4;
    int c0 = 2 * cg, r0 = 2 * rg;
    int row_base = by * 16, col_base = bx * 32;

    const float* inb = in + (size_t)b * CIN_ * HW_;
    float acc[11][4] = {};

    for (int ch = 0; ch < CIN_ / CK; ++ch) {
        int ci0 = ch * CK;
        __syncthreads();
        for (int idx = tid; idx < CK * 18 * 34; idx += 128) {
            int ci = idx / 612;
            int rem = idx - ci * 612;
            int r = rem / 34, c = rem - r * 34;
            int gr = row_base - 1 + r, gc = col_base - 1 + c;
            float v = 0.f;
            if ((unsigned)gr < 180u && (unsigned)gc < 180u)
                v = inb[(size_t)(ci0 + ci) * HW_ + gr * FW_ + gc];
            lin[ci * 648 + r * 36 + c] = v;
        }
        for (int idx = tid; idx < 216; idx += 128) {
            float4 w4 = *(const float4*)&wTh[(size_t)ci0 * 108 + idx * 4];
            *(float4*)&lw[idx * 4] = w4;
        }
        __syncthreads();

#pragma unroll 1
        for (int ci = 0; ci < CK; ++ci) {
            float xv[4][4];
#pragma unroll
            for (int rr = 0; rr < 4; ++rr) {
                const float* lp = &lin[ci * 648 + (r0 + rr) * 36 + c0];
                float2 a = *(const float2*)lp;
                float2 bv = *(const float2*)(lp + 2);
                xv[rr][0] = a.x; xv[rr][1] = a.y; xv[rr][2] = bv.x; xv[rr][3] = bv.y;
            }
#pragma unroll
            for (int k = 0; k < 9; ++k) {
                int kr = k / 3, kc = k % 3;
                const float* wp = &lw[(ci * 9 + k) * 12];
#pragma unroll
                for (int co = 0; co < 11; ++co) {
                    float w = wp[co];
#pragma unroll
                    for (int r = 0; r < 2; ++r)
#pragma unroll
                        for (int c = 0; c < 2; ++c)
                            acc[co][r * 2 + c] = fmaf(w, xv[r + kr][c + kc], acc[co][r * 2 + c]);
                }
            }
        }
    }

    int gc0 = col_base + c0;
    if (gc0 < FW_) {
#pragma unroll
        for (int co = 0; co < 11; ++co) {
            float bias = (co < 2) ? hb[co] : rb[co - 2];
            float* basep = (co < 2)
                ? (out + HM_OFF  + (size_t)(b * 2 + co) * HW_)
                : (out + REG_OFF + (size_t)(b * 9 + (co - 2)) * HW_);
#pragma unroll
            for (int r = 0; r < 2; ++r) {
                int gr = row_base + r0 + r;
                if (gr < FH_) {
                    float2 o;
                    o.x = acc[co][r * 2 + 0] + bias;
                    o.y = acc[co][r * 2 + 1] + bias;
                    *(float2*)&basep[(size_t)gr * FW_ + gc0] = o;
                }
            }
        }
    }
}

// ---------------------------------------------------------------------------
// targets (unchanged from round 1 — validated)
// ---------------------------------------------------------------------------
__global__ void k_zero_heat(float* __restrict__ out)
{
    int i = blockIdx.x * 256 + threadIdx.x;
    if (i < BB_ * 2 * HW_) out[HEAT_OFF + i] = 0.f;
}

__global__ void k_objects(const float* __restrict__ gt, float* __restrict__ out)
{
    int ob = blockIdx.x;
    int b = ob / MM_, m = ob % MM_;
    const float* gp = gt + (size_t)ob * 8;
    float x = gp[0], y = gp[1], z = gp[2];
    float dx = gp[3], dy = gp[4], dz = gp[5], ry = gp[6];
    int cls = (int)gp[7];

    float coord_x = fminf(fmaxf((x + 54.f) / 0.075f / 8.f, 0.f), 179.5f);
    float coord_y = fminf(fmaxf((y + 54.f) / 0.075f / 8.f, 0.f), 179.5f);
    int cxi = (int)coord_x, cyi = (int)coord_y;
    float dxp = dx / 0.075f / 8.f;
    float dyp = dy / 0.075f / 8.f;

    float hgt = dxp, wid = dyp, mo = 0.1f;
    float b1 = hgt + wid, c1 = wid * hgt * (1.f - mo) / (1.f + mo);
    float r1 = (b1 + sqrtf(fmaxf(b1 * b1 - 4.f * c1, 0.f))) * 0.5f;
    float b2 = 2.f * (hgt + wid), c2 = (1.f - mo) * wid * hgt;
    float r2 = (b2 + sqrtf(fmaxf(b2 * b2 - 16.f * c2, 0.f))) * 0.5f;
    float a3 = 4.f * mo, b3 = -2.f * mo * (hgt + wid), c3 = (mo - 1.f) * wid * hgt;
    float r3 = (b3 + sqrtf(fmaxf(b3 * b3 - 4.f * a3 * c3, 0.f))) / (2.f * a3);
    int radius = max((int)fminf(fminf(r1, r2), r3), 2);

    bool valid = (dxp > 0.f) && (dyp > 0.f);
    bool pos = valid && (cls >= 1);

    if (threadIdx.x == 0) {
        float m0 = valid ? (cls >= 1 ? 1.f : -1.f) : 0.f;
        bool w_cond = (0.075f * 8.f) > dy / 4.f;
        bool l_cond = (0.075f * 8.f) > dx / 4.f;
        bool s1 = valid && !w_cond && (cxi - 1 >= 0);
        bool s2 = valid && !w_cond && (cxi + 1 < FW_);
        bool s3 = valid && !l_cond && (cyi - 1 >= 0);
        bool s4 = valid && !l_cond && (cyi + 1 < FH_);
        int base_ind = cyi * FW_ + cxi;

        float* indp = out + IND_OFF + (size_t)b * MM_ * 5 + m * 5;
        float* mskp = out + MSK_OFF + (size_t)b * MM_ * 5 + m * 5;
        indp[0] = valid ? (float)base_ind : 0.f;
        indp[1] = s1 ? (float)(base_ind - 1) : 0.f;
        indp[2] = s2 ? (float)(base_ind + 1) : 0.f;
        indp[3] = s3 ? (float)(base_ind - FW_) : 0.f;
        indp[4] = s4 ? (float)(base_ind + FW_) : 0.f;
        mskp[0] = m0;
        mskp[1] = s1 ? m0 : 0.f;
        mskp[2] = s2 ? m0 : 0.f;
        mskp[3] = s3 ? m0 : 0.f;
        mskp[4] = s4 ? m0 : 0.f;

        float offx = coord_x - (float)cxi;
        float offy = coord_y - (float)cyi;
        float bse[8] = { offx, offy, z,
                         logf(fmaxf(dx, 1e-8f)), logf(fmaxf(dy, 1e-8f)),
                         logf(fmaxf(dz, 1e-8f)), cosf(ry), sinf(ry) };
        float vm = valid ? 1.f : 0.f;
        float* rbp = out + RB_OFF + ((size_t)b * MM_ + m) * 5 * 8;
#pragma unroll
        for (int s = 0; s < 5; ++s) {
            float t0 = bse[0], t1 = bse[1];
            if (s == 1) t0 += s1 ? 1.f : 0.f;
            if (s == 2) t0 -= s2 ? 1.f : 0.f;
            if (s == 3) t1 += s3 ? 1.f : 0.f;
            if (s == 4) t1 -= s4 ? 1.f : 0.f;
            rbp[s * 8 + 0] = t0 * vm;
            rbp[s * 8 + 1] = t1 * vm;
#pragma unroll
            for (int k = 2; k < 8; ++k) rbp[s * 8 + k] = bse[k] * vm;
        }
    }

    if (pos) {
        float sigma = (2.f * (float)radius + 1.f) / 6.f;
        float inv2s2 = 1.f / (2.f * sigma * sigma);
        int x0 = max(cxi - radius, 0), x1 = min(cxi + radius, FW_ - 1);
        int y0 = max(cyi - radius, 0), y1 = min(cyi + radius, FH_ - 1);
        int wdt = x1 - x0 + 1, tot = wdt * (y1 - y0 + 1);
        float* hp = out + HEAT_OFF + (size_t)(b * 2 + (cls - 1)) * HW_;
        for (int i = threadIdx.x; i < tot; i += blockDim.x) {
            int yy = y0 + i / wdt, xx = x0 + i % wdt;
            float ddy = (float)(yy - cyi), ddx = (float)(xx - cxi);
            float gvl = expf(-(ddy * ddy + ddx * ddx) * inv2s2);
            atomicMax((int*)(hp + yy * FW_ + xx), __float_as_int(gvl));
        }
    }
}

__global__ void k_hm_mask(float* __restrict__ out)
{
    int i = blockIdx.x * 256 + threadIdx.x;
    if (i < BB_ * 2 * HW_) {
        float v = out[HEAT_OFF + i];
        out[HMM_OFF + i] = v > 0.f ? 1.f : 0.f;
    }
}

// ---------------------------------------------------------------------------
extern "C" void kernel_launch(void* const* d_in, const int* in_sizes, int n_in,
                              void* d_out, int out_size, void* d_ws, size_t ws_size,
                              hipStream_t stream)
{
    const float* x  = (const float*)d_in[0];
    const float* gt = (const float*)d_in[1];
    const float* w1 = (const float*)d_in[2];
    const float* g1 = (const float*)d_in[3];
    const float* b1 = (const float*)d_in[4];
    const float* m1 = (const float*)d_in[5];
    const float* v1 = (const float*)d_in[6];
    const float* w2 = (const float*)d_in[7];
    const float* g2 = (const float*)d_in[8];
    const float* b2 = (const float*)d_in[9];
    const float* m2 = (const float*)d_in[10];
    const float* v2 = (const float*)d_in[11];
    const float* hw = (const float*)d_in[12];
    const float* hb = (const float*)d_in[13];
    const float* rw = (const float*)d_in[14];
    const float* rb = (const float*)d_in[15];
    float* out = (float*)d_out;

    const size_t FSZ = (size_t)BB_ * CIN_ * HW_;    // feature map floats
    float* f1 = (float*)d_ws;
    float* f2 = f1 + FSZ;
    // scratch aliasing (all orderings sequential on stream):
    float* wT1 = f2;                 // dead until conv2 writes f2
    float* wT2 = out + REG_OFF;      // overwritten later by k_head_t
    float* wTh = out + RB_OFF;       // overwritten later by k_objects

    k_prep_wT <<<(CIN_*CIN_*9 + 255)/256, 256, 0, stream>>>(w1, wT1);
    k_prep_wT <<<(CIN_*CIN_*9 + 255)/256, 256, 0, stream>>>(w2, wT2);
    k_prep_wTh<<<(CIN_*9*12 + 255)/256, 256, 0, stream>>>(hw, rw, wTh);

    dim3 cg(144, 2, BB_);
    k_conv_t<<<cg, 256, 0, stream>>>(x,  wT1, g1, b1, m1, v1, f1);
    k_conv_t<<<cg, 256, 0, stream>>>(f1, wT2, g2, b2, m2, v2, f2);

    dim3 hg(72, BB_);
    k_head_t<<<hg, 128, 0, stream>>>(f2, wTh, hb, rb, out);

    k_zero_heat<<<(BB_*2*HW_ + 255)/256, 256, 0, stream>>>(out);
    k_objects<<<BB_*MM_, 64, 0, stream>>>(gt, out);
    k_hm_mask<<<(BB_*2*HW_ + 255)/256, 256, 0, stream>>>(out);
}

// Round 3
// 344.744 us; speedup vs baseline: 13.2526x; 4.1776x over previous
//
#include <hip/hip_runtime.h>
#include <math.h>

typedef unsigned short u16;
typedef short bf16x8 __attribute__((ext_vector_type(8)));
typedef float f32x4 __attribute__((ext_vector_type(4)));

#define FW_ 180
#define FH_ 180
#define HW_ (FW_*FH_)
#define CIN_ 128
#define BB_ 4
#define MM_ 500
#define PW_ 182
#define PADE ((size_t)BB_*PW_*PW_*CIN_)   // elems per padded feature buffer

// d_out segment offsets (floats), in reference return order
#define HM_OFF   0
#define REG_OFF  (BB_*2*HW_)                   // 259200
#define HEAT_OFF (REG_OFF + BB_*9*HW_)         // 1425600
#define RB_OFF   (HEAT_OFF + BB_*2*HW_)        // 1684800
#define IND_OFF  (RB_OFF + BB_*MM_*5*8)        // 1764800
#define MSK_OFF  (IND_OFF + BB_*MM_*5)         // 1774800
#define HMM_OFF  (MSK_OFF + BB_*MM_*5)         // 1784800

__device__ inline u16 f2bf(float f) {
    unsigned u = __float_as_uint(f);
    u += 0x7FFFu + ((u >> 16) & 1u);           // RNE
    return (u16)(u >> 16);
}

// ---------------------------------------------------------------------------
// zero the 1-px borders of the three padded channel-last buffers (every call)
// ---------------------------------------------------------------------------
__global__ void k_zero_borders(u16* __restrict__ ws)
{
    int idx = blockIdx.x * 256 + threadIdx.x;
    if (idx >= 3 * BB_ * PW_ * PW_) return;
    int buf = idx / (BB_ * PW_ * PW_);
    int rem = idx % (BB_ * PW_ * PW_);
    int p = rem % (PW_ * PW_);
    int r = p / PW_, c = p % PW_;
    if (r > 0 && r < PW_ - 1 && c > 0 && c < PW_ - 1) return;
    u16* base = ws + (size_t)buf * PADE + (size_t)rem * CIN_;
#pragma unroll
    for (int i = 0; i < 16; ++i) ((uint4*)base)[i] = make_uint4(0, 0, 0, 0);
}

// ---------------------------------------------------------------------------
// x (f32 NCHW) -> xT (bf16, [b][row+1][col+1][ci], channel-last padded)
// ---------------------------------------------------------------------------
__global__ __launch_bounds__(256) void k_prep_xT(const float* __restrict__ in,
                                                 u16* __restrict__ xT)
{
    __shared__ u16 lt[180 * 130];              // [col][ci], pad 130 -> conflict-free
    int tid = threadIdx.x;
    int row = blockIdx.x, b = blockIdx.y;
    for (int ci = 0; ci < CIN_; ++ci) {
        if (tid < 180) {
            float v = in[(((size_t)b * CIN_ + ci) * FH_ + row) * FW_ + tid];
            lt[tid * 130 + ci] = f2bf(v);
        }
    }
    __syncthreads();
    unsigned* dst = (unsigned*)(xT + ((size_t)b * PW_ * PW_ + (size_t)(row + 1) * PW_ + 1) * CIN_);
    for (int idx = tid; idx < 180 * 64; idx += 256) {
        int col = idx >> 6, c2 = idx & 63;
        unsigned lo = lt[col * 130 + 2 * c2];
        unsigned hi = lt[col * 130 + 2 * c2 + 1];
        dst[col * 64 + c2] = lo | (hi << 16);
    }
}

// w[co][ci][3][3] f32 -> wT[tap][co][ci] bf16
__global__ void k_prep_wT(const float* __restrict__ w, u16* __restrict__ wT)
{
    int i = blockIdx.x * 256 + threadIdx.x;
    if (i >= 9 * CIN_ * CIN_) return;
    int tap = i / (CIN_ * CIN_);
    int r = i % (CIN_ * CIN_);
    int co = r >> 7, ci = r & 127;
    wT[i] = f2bf(w[((size_t)co * CIN_ + ci) * 9 + tap]);
}

// hm(2)+reg(9) weights -> wTh[tap][co16(pad)][ci] bf16
__global__ void k_prep_wTh(const float* __restrict__ hw, const float* __restrict__ rw,
                           u16* __restrict__ wTh)
{
    int i = blockIdx.x * 256 + threadIdx.x;
    if (i >= 9 * 16 * CIN_) return;
    int tap = i / (16 * CIN_);
    int r = i % (16 * CIN_);
    int co = r >> 7, ci = r & 127;
    float v = 0.f;
    if (co < 2)       v = hw[((size_t)co * CIN_ + ci) * 9 + tap];
    else if (co < 11) v = rw[((size_t)(co - 2) * CIN_ + ci) * 9 + tap];
    wTh[i] = f2bf(v);
}

// ---------------------------------------------------------------------------
// conv 3x3 SAME 128->128 + BN + ReLU via mfma_f32_16x16x32_bf16.
// Block = 2 waves; wave w: co w*64..+63 (4 m-frags), px = 4 rows x 16 cols
// (4 n-frags). K = 9 taps x 128 ci. All operands loaded straight from
// global (L1/L2-resident), no LDS.
// ---------------------------------------------------------------------------
__global__ __launch_bounds__(128) void k_conv_mfma(
    const u16* __restrict__ xT, const u16* __restrict__ wT,
    const float* __restrict__ gg, const float* __restrict__ bbn,
    const float* __restrict__ mmn, const float* __restrict__ vvn,
    u16* __restrict__ yT)
{
    int wave = threadIdx.x >> 6;
    int lane = threadIdx.x & 63;
    int lm = lane & 15, hi = lane >> 4;
    int C0 = min((int)blockIdx.x * 16, 164);
    int R0 = blockIdx.y * 4;
    int b  = blockIdx.z;
    const u16* xb = xT + (size_t)b * PW_ * PW_ * CIN_;

    f32x4 acc[4][4];
#pragma unroll
    for (int i = 0; i < 4; ++i)
#pragma unroll
        for (int j = 0; j < 4; ++j) acc[i][j] = (f32x4){0.f, 0.f, 0.f, 0.f};

    const u16* aB = wT + ((size_t)wave * 64 + lm) * CIN_ + hi * 8;
    const u16* bB = xb + ((size_t)R0 * PW_ + C0 + lm) * CIN_ + hi * 8;

    for (int ci0 = 0; ci0 < CIN_; ci0 += 32) {
#pragma unroll
        for (int tap = 0; tap < 9; ++tap) {
            const int kr = tap / 3, kc = tap - 3 * (tap / 3);
            bf16x8 av[4], bv[4];
#pragma unroll
            for (int mf = 0; mf < 4; ++mf)
                av[mf] = *(const bf16x8*)(aB + tap * (CIN_ * CIN_) + mf * 16 * CIN_ + ci0);
#pragma unroll
            for (int nf = 0; nf < 4; ++nf)
                bv[nf] = *(const bf16x8*)(bB + ((kr + nf) * PW_ + kc) * CIN_ + ci0);
#pragma unroll
            for (int mf = 0; mf < 4; ++mf)
#pragma unroll
                for (int nf = 0; nf < 4; ++nf)
                    acc[mf][nf] = __builtin_amdgcn_mfma_f32_16x16x32_bf16(
                        av[mf], bv[nf], acc[mf][nf], 0, 0, 0);
        }
    }

    // epilogue: BN + ReLU, pack 4 co (bf16) per lane, store 8B
#pragma unroll
    for (int mf = 0; mf < 4; ++mf) {
        int co0 = wave * 64 + mf * 16 + hi * 4;
        float4 g4 = *(const float4*)(gg + co0);
        float4 b4 = *(const float4*)(bbn + co0);
        float4 m4 = *(const float4*)(mmn + co0);
        float4 v4 = *(const float4*)(vvn + co0);
        float sc0 = g4.x / sqrtf(v4.x + 1e-5f), sh0 = b4.x - m4.x * sc0;
        float sc1 = g4.y / sqrtf(v4.y + 1e-5f), sh1 = b4.y - m4.y * sc1;
        float sc2 = g4.z / sqrtf(v4.z + 1e-5f), sh2 = b4.z - m4.z * sc2;
        float sc3 = g4.w / sqrtf(v4.w + 1e-5f), sh3 = b4.w - m4.w * sc3;
#pragma unroll
        for (int nf = 0; nf < 4; ++nf) {
            f32x4 A = acc[mf][nf];
            float y0 = fmaxf(fmaf(A[0], sc0, sh0), 0.f);
            float y1 = fmaxf(fmaf(A[1], sc1, sh1), 0.f);
            float y2 = fmaxf(fmaf(A[2], sc2, sh2), 0.f);
            float y3 = fmaxf(fmaf(A[3], sc3, sh3), 0.f);
            unsigned p0 = (unsigned)f2bf(y0) | ((unsigned)f2bf(y1) << 16);
            unsigned p1 = (unsigned)f2bf(y2) | ((unsigned)f2bf(y3) << 16);
            u16* op = yT + (size_t)b * PW_ * PW_ * CIN_ +
                      ((size_t)(R0 + nf + 1) * PW_ + (C0 + lm + 1)) * CIN_ + co0;
            *(uint2*)op = make_uint2(p0, p1);
        }
    }
}

// ---------------------------------------------------------------------------
// head: 11 outputs (2 hm + 9 reg) via MFMA, co padded to 16.
// Block = 4 waves; wave w: rows R0+w*4..+3, cols C0..C0+15. f32 NCHW out.
// ---------------------------------------------------------------------------
__global__ __launch_bounds__(256) void k_head_mfma(
    const u16* __restrict__ f2T, const u16* __restrict__ wTh,
    const float* __restrict__ hb, const float* __restrict__ rb,
    float* __restrict__ out)
{
    int wave = threadIdx.x >> 6;
    int lane = threadIdx.x & 63;
    int lm = lane & 15, hi = lane >> 4;
    int C0 = min((int)blockIdx.x * 16, 164);
    int R0 = min((int)blockIdx.y * 16, 164);
    int b  = blockIdx.z;
    int RW = R0 + wave * 4;
    const u16* xb = f2T + (size_t)b * PW_ * PW_ * CIN_;

    f32x4 acc[4];
#pragma unroll
    for (int i = 0; i < 4; ++i) acc[i] = (f32x4){0.f, 0.f, 0.f, 0.f};

    const u16* aB = wTh + (size_t)lm * CIN_ + hi * 8;
    const u16* bB = xb + ((size_t)RW * PW_ + C0 + lm) * CIN_ + hi * 8;

    for (int ci0 = 0; ci0 < CIN_; ci0 += 32) {
#pragma unroll
        for (int tap = 0; tap < 9; ++tap) {
            const int kr = tap / 3, kc = tap - 3 * (tap / 3);
            bf16x8 av = *(const bf16x8*)(aB + tap * (16 * CIN_) + ci0);
            bf16x8 bv[4];
#pragma unroll
            for (int nf = 0; nf < 4; ++nf)
                bv[nf] = *(const bf16x8*)(bB + ((kr + nf) * PW_ + kc) * CIN_ + ci0);
#pragma unroll
            for (int nf = 0; nf < 4; ++nf)
                acc[nf] = __builtin_amdgcn_mfma_f32_16x16x32_bf16(av, bv[nf], acc[nf], 0, 0, 0);
        }
    }

#pragma unroll
    for (int nf = 0; nf < 4; ++nf) {
        int row = RW + nf, col = C0 + lm;
        f32x4 A = acc[nf];
#pragma unroll
        for (int r = 0; r < 4; ++r) {
            int co = hi * 4 + r;
            float v = A[r];
            if (co < 2)
                out[HM_OFF + ((size_t)(b * 2 + co)) * HW_ + row * FW_ + col] = v + hb[co];
            else if (co < 11)
                out[REG_OFF + ((size_t)(b * 9 + co - 2)) * HW_ + row * FW_ + col] = v + rb[co - 2];
        }
    }
}

// ---------------------------------------------------------------------------
// targets (unchanged — validated rounds 1-2)
// ---------------------------------------------------------------------------
__global__ void k_zero_heat(float* __restrict__ out)
{
    int i = blockIdx.x * 256 + threadIdx.x;
    if (i < BB_ * 2 * HW_) out[HEAT_OFF + i] = 0.f;
}

__global__ void k_objects(const float* __restrict__ gt, float* __restrict__ out)
{
    int ob = blockIdx.x;
    int b = ob / MM_, m = ob % MM_;
    const float* gp = gt + (size_t)ob * 8;
    float x = gp[0], y = gp[1], z = gp[2];
    float dx = gp[3], dy = gp[4], dz = gp[5], ry = gp[6];
    int cls = (int)gp[7];

    float coord_x = fminf(fmaxf((x + 54.f) / 0.075f / 8.f, 0.f), 179.5f);
    float coord_y = fminf(fmaxf((y + 54.f) / 0.075f / 8.f, 0.f), 179.5f);
    int cxi = (int)coord_x, cyi = (int)coord_y;
    float dxp = dx / 0.075f / 8.f;
    float dyp = dy / 0.075f / 8.f;

    float hgt = dxp, wid = dyp, mo = 0.1f;
    float b1 = hgt + wid, c1 = wid * hgt * (1.f - mo) / (1.f + mo);
    float r1 = (b1 + sqrtf(fmaxf(b1 * b1 - 4.f * c1, 0.f))) * 0.5f;
    float b2 = 2.f * (hgt + wid), c2 = (1.f - mo) * wid * hgt;
    float r2 = (b2 + sqrtf(fmaxf(b2 * b2 - 16.f * c2, 0.f))) * 0.5f;
    float a3 = 4.f * mo, b3 = -2.f * mo * (hgt + wid), c3 = (mo - 1.f) * wid * hgt;
    float r3 = (b3 + sqrtf(fmaxf(b3 * b3 - 4.f * a3 * c3, 0.f))) / (2.f * a3);
    int radius = max((int)fminf(fminf(r1, r2), r3), 2);

    bool valid = (dxp > 0.f) && (dyp > 0.f);
    bool pos = valid && (cls >= 1);

    if (threadIdx.x == 0) {
        float m0 = valid ? (cls >= 1 ? 1.f : -1.f) : 0.f;
        bool w_cond = (0.075f * 8.f) > dy / 4.f;
        bool l_cond = (0.075f * 8.f) > dx / 4.f;
        bool s1 = valid && !w_cond && (cxi - 1 >= 0);
        bool s2 = valid && !w_cond && (cxi + 1 < FW_);
        bool s3 = valid && !l_cond && (cyi - 1 >= 0);
        bool s4 = valid && !l_cond && (cyi + 1 < FH_);
        int base_ind = cyi * FW_ + cxi;

        float* indp = out + IND_OFF + (size_t)b * MM_ * 5 + m * 5;
        float* mskp = out + MSK_OFF + (size_t)b * MM_ * 5 + m * 5;
        indp[0] = valid ? (float)base_ind : 0.f;
        indp[1] = s1 ? (float)(base_ind - 1) : 0.f;
        indp[2] = s2 ? (float)(base_ind + 1) : 0.f;
        indp[3] = s3 ? (float)(base_ind - FW_) : 0.f;
        indp[4] = s4 ? (float)(base_ind + FW_) : 0.f;
        mskp[0] = m0;
        mskp[1] = s1 ? m0 : 0.f;
        mskp[2] = s2 ? m0 : 0.f;
        mskp[3] = s3 ? m0 : 0.f;
        mskp[4] = s4 ? m0 : 0.f;

        float offx = coord_x - (float)cxi;
        float offy = coord_y - (float)cyi;
        float bse[8] = { offx, offy, z,
                         logf(fmaxf(dx, 1e-8f)), logf(fmaxf(dy, 1e-8f)),
                         logf(fmaxf(dz, 1e-8f)), cosf(ry), sinf(ry) };
        float vm = valid ? 1.f : 0.f;
        float* rbp = out + RB_OFF + ((size_t)b * MM_ + m) * 5 * 8;
#pragma unroll
        for (int s = 0; s < 5; ++s) {
            float t0 = bse[0], t1 = bse[1];
            if (s == 1) t0 += s1 ? 1.f : 0.f;
            if (s == 2) t0 -= s2 ? 1.f : 0.f;
            if (s == 3) t1 += s3 ? 1.f : 0.f;
            if (s == 4) t1 -= s4 ? 1.f : 0.f;
            rbp[s * 8 + 0] = t0 * vm;
            rbp[s * 8 + 1] = t1 * vm;
#pragma unroll
            for (int k = 2; k < 8; ++k) rbp[s * 8 + k] = bse[k] * vm;
        }
    }

    if (pos) {
        float sigma = (2.f * (float)radius + 1.f) / 6.f;
        float inv2s2 = 1.f / (2.f * sigma * sigma);
        int x0 = max(cxi - radius, 0), x1 = min(cxi + radius, FW_ - 1);
        int y0 = max(cyi - radius, 0), y1 = min(cyi + radius, FH_ - 1);
        int wdt = x1 - x0 + 1, tot = wdt * (y1 - y0 + 1);
        float* hp = out + HEAT_OFF + (size_t)(b * 2 + (cls - 1)) * HW_;
        for (int i = threadIdx.x; i < tot; i += blockDim.x) {
            int yy = y0 + i / wdt, xx = x0 + i % wdt;
            float ddy = (float)(yy - cyi), ddx = (float)(xx - cxi);
            float gvl = expf(-(ddy * ddy + ddx * ddx) * inv2s2);
            atomicMax((int*)(hp + yy * FW_ + xx), __float_as_int(gvl));
        }
    }
}

__global__ void k_hm_mask(float* __restrict__ out)
{
    int i = blockIdx.x * 256 + threadIdx.x;
    if (i < BB_ * 2 * HW_) {
        float v = out[HEAT_OFF + i];
        out[HMM_OFF + i] = v > 0.f ? 1.f : 0.f;
    }
}

// ---------------------------------------------------------------------------
extern "C" void kernel_launch(void* const* d_in, const int* in_sizes, int n_in,
                              void* d_out, int out_size, void* d_ws, size_t ws_size,
                              hipStream_t stream)
{
    const float* x  = (const float*)d_in[0];
    const float* gt = (const float*)d_in[1];
    const float* w1 = (const float*)d_in[2];
    const float* g1 = (const float*)d_in[3];
    const float* b1 = (const float*)d_in[4];
    const float* m1 = (const float*)d_in[5];
    const float* v1 = (const float*)d_in[6];
    const float* w2 = (const float*)d_in[7];
    const float* g2 = (const float*)d_in[8];
    const float* b2 = (const float*)d_in[9];
    const float* m2 = (const float*)d_in[10];
    const float* v2 = (const float*)d_in[11];
    const float* hw = (const float*)d_in[12];
    const float* hb = (const float*)d_in[13];
    const float* rw = (const float*)d_in[14];
    const float* rb = (const float*)d_in[15];
    float* out = (float*)d_out;

    u16* ws  = (u16*)d_ws;
    u16* xT  = ws;                       // padded channel-last bf16 buffers
    u16* f1T = ws + PADE;
    u16* f2T = ws + 2 * PADE;
    u16* wT1 = ws + 3 * PADE;            // 9*128*128
    u16* wT2 = wT1 + 9 * CIN_ * CIN_;
    u16* wTh = wT2 + 9 * CIN_ * CIN_;    // 9*16*128

    k_zero_borders<<<(3 * BB_ * PW_ * PW_ + 255) / 256, 256, 0, stream>>>(ws);
    k_prep_xT<<<dim3(180, BB_), 256, 0, stream>>>(x, xT);
    k_prep_wT<<<(9 * CIN_ * CIN_ + 255) / 256, 256, 0, stream>>>(w1, wT1);
    k_prep_wT<<<(9 * CIN_ * CIN_ + 255) / 256, 256, 0, stream>>>(w2, wT2);
    k_prep_wTh<<<(9 * 16 * CIN_ + 255) / 256, 256, 0, stream>>>(hw, rw, wTh);

    dim3 cg(12, 45, BB_);
    k_conv_mfma<<<cg, 128, 0, stream>>>(xT,  wT1, g1, b1, m1, v1, f1T);
    k_conv_mfma<<<cg, 128, 0, stream>>>(f1T, wT2, g2, b2, m2, v2, f2T);

    dim3 hg(12, 12, BB_);
    k_head_mfma<<<hg, 256, 0, stream>>>(f2T, wTh, hb, rb, out);

    k_zero_heat<<<(BB_ * 2 * HW_ + 255) / 256, 256, 0, stream>>>(out);
    k_objects<<<BB_ * MM_, 64, 0, stream>>>(gt, out);
    k_hm_mask<<<(BB_ * 2 * HW_ + 255) / 256, 256, 0, stream>>>(out);
}

// Round 4
// 207.436 us; speedup vs baseline: 22.0248x; 1.6619x over previous
//
#include <hip/hip_runtime.h>
#include <math.h>

typedef unsigned short u16;
typedef short bf16x8 __attribute__((ext_vector_type(8)));
typedef float f32x4 __attribute__((ext_vector_type(4)));

#define FW_ 180
#define FH_ 180
#define HW_ (FW_*FH_)
#define CIN_ 128
#define BB_ 4
#define MM_ 500
#define PW_ 182
#define PADE ((size_t)BB_*PW_*PW_*CIN_)   // elems per padded feature buffer

// d_out segment offsets (floats), in reference return order
#define HM_OFF   0
#define REG_OFF  (BB_*2*HW_)                   // 259200
#define HEAT_OFF (REG_OFF + BB_*9*HW_)         // 1425600
#define RB_OFF   (HEAT_OFF + BB_*2*HW_)        // 1684800
#define IND_OFF  (RB_OFF + BB_*MM_*5*8)        // 1764800
#define MSK_OFF  (IND_OFF + BB_*MM_*5)         // 1774800
#define HMM_OFF  (MSK_OFF + BB_*MM_*5)         // 1784800

__device__ inline u16 f2bf(float f) {
    unsigned u = __float_as_uint(f);
    u += 0x7FFFu + ((u >> 16) & 1u);           // RNE
    return (u16)(u >> 16);
}

#define GLOAD_LDS16(gsrc, ldst) \
    __builtin_amdgcn_global_load_lds( \
        (const __attribute__((address_space(1))) unsigned*)(gsrc), \
        (__attribute__((address_space(3))) unsigned*)(ldst), 16, 0, 0)

// ---------------------------------------------------------------------------
// zero the 1-px borders of the three padded channel-last buffers
// ---------------------------------------------------------------------------
__global__ void k_zero_borders(u16* __restrict__ ws)
{
    int idx = blockIdx.x * 256 + threadIdx.x;
    if (idx >= 3 * BB_ * PW_ * PW_) return;
    int buf = idx / (BB_ * PW_ * PW_);
    int rem = idx % (BB_ * PW_ * PW_);
    int p = rem % (PW_ * PW_);
    int r = p / PW_, c = p % PW_;
    if (r > 0 && r < PW_ - 1 && c > 0 && c < PW_ - 1) return;
    u16* base = ws + (size_t)buf * PADE + (size_t)rem * CIN_;
#pragma unroll
    for (int i = 0; i < 16; ++i) ((uint4*)base)[i] = make_uint4(0, 0, 0, 0);
}

// ---------------------------------------------------------------------------
// x (f32 NCHW) -> xT (bf16, [b][row+1][col+1][ci], channel-last padded)
// ---------------------------------------------------------------------------
__global__ __launch_bounds__(256) void k_prep_xT(const float* __restrict__ in,
                                                 u16* __restrict__ xT)
{
    __shared__ u16 lt[180 * 130];
    int tid = threadIdx.x;
    int row = blockIdx.x, b = blockIdx.y;
    for (int ci = 0; ci < CIN_; ++ci) {
        if (tid < 180) {
            float v = in[(((size_t)b * CIN_ + ci) * FH_ + row) * FW_ + tid];
            lt[tid * 130 + ci] = f2bf(v);
        }
    }
    __syncthreads();
    unsigned* dst = (unsigned*)(xT + ((size_t)b * PW_ * PW_ + (size_t)(row + 1) * PW_ + 1) * CIN_);
    for (int idx = tid; idx < 180 * 64; idx += 256) {
        int col = idx >> 6, c2 = idx & 63;
        unsigned lo = lt[col * 130 + 2 * c2];
        unsigned hi = lt[col * 130 + 2 * c2 + 1];
        dst[col * 64 + c2] = lo | (hi << 16);
    }
}

// w[co][ci][3][3] f32 -> wT[tap][co][ci] bf16
__global__ void k_prep_wT(const float* __restrict__ w, u16* __restrict__ wT)
{
    int i = blockIdx.x * 256 + threadIdx.x;
    if (i >= 9 * CIN_ * CIN_) return;
    int tap = i / (CIN_ * CIN_);
    int r = i % (CIN_ * CIN_);
    int co = r >> 7, ci = r & 127;
    wT[i] = f2bf(w[((size_t)co * CIN_ + ci) * 9 + tap]);
}

// hm(2)+reg(9) weights -> wTh[tap][co16(pad)][ci] bf16
__global__ void k_prep_wTh(const float* __restrict__ hw, const float* __restrict__ rw,
                           u16* __restrict__ wTh)
{
    int i = blockIdx.x * 256 + threadIdx.x;
    if (i >= 9 * 16 * CIN_) return;
    int tap = i / (16 * CIN_);
    int r = i % (16 * CIN_);
    int co = r >> 7, ci = r & 127;
    float v = 0.f;
    if (co < 2)       v = hw[((size_t)co * CIN_ + ci) * 9 + tap];
    else if (co < 11) v = rw[((size_t)(co - 2) * CIN_ + ci) * 9 + tap];
    wTh[i] = f2bf(v);
}

// ---------------------------------------------------------------------------
// conv 3x3 SAME 128->128 + BN + ReLU, MFMA + LDS (m97-style 2-barrier loop).
// Block: 8 waves, out tile 128 co x 4 rows x 64 cols. Wave (wm,wn):
// co wm*64..+63 (4 m-frags) x 16 cols (wn*16, as n... rows are the 4 nf).
// Per ci-chunk(32): input halo 6x66x32 staged once; weights per tap (8 KB)
// double-buffered. XOR-swizzled LDS units (q ^= (c>>1)&3) for conflict-free
// b128 reads; sources pre-swizzled to keep global_load_lds dest linear.
// ---------------------------------------------------------------------------
__global__ __launch_bounds__(512, 4) void k_conv_mfma2(
    const u16* __restrict__ xT, const u16* __restrict__ wT,
    const float* __restrict__ gg, const float* __restrict__ bbn,
    const float* __restrict__ mmn, const float* __restrict__ vvn,
    u16* __restrict__ yT)
{
    __shared__ u16 lin[2048 * 8];        // 32 KB: [rc = r*66+c][4 units][8 ci] swizzled
    __shared__ u16 lwt[2][512 * 8];      // 8 KB x2: [co][4 units][8 ci] swizzled

    int tid  = threadIdx.x;
    int wv   = tid >> 6, lane = tid & 63;
    int lm   = lane & 15, hi = lane >> 4;
    int wm   = wv >> 2, wn = wv & 3;
    int C0   = (blockIdx.x == 2) ? 116 : (int)blockIdx.x * 64;
    int R0   = blockIdx.y * 4;
    int b    = blockIdx.z;
    const u16* xb = xT + (size_t)b * PW_ * PW_ * CIN_;

    f32x4 acc[4][4];
#pragma unroll
    for (int i = 0; i < 4; ++i)
#pragma unroll
        for (int j = 0; j < 4; ++j) acc[i][j] = (f32x4){0.f, 0.f, 0.f, 0.f};

    // weight-stage slot (same lane->slot map every tap)
    const int oA  = tid;
    const int coA = oA >> 2;
    const int qA  = (oA & 3) ^ ((coA >> 1) & 3);
    const size_t woff = ((size_t)coA) * CIN_ + qA * 8;

#pragma unroll 1
    for (int ch = 0; ch < 4; ++ch) {
        int ci0 = ch * 32;
        // ---- stage input halo chunk: 1584 live units, 2048 staged ----
#pragma unroll
        for (int rd = 0; rd < 4; ++rd) {
            int o = rd * 512 + tid;
            int rc = o >> 2;
            int r = rc / 66, c = rc - 66 * r;
            if (o >= 1584) { r = 0; c = 0; }
            int q = (o & 3) ^ ((c >> 1) & 3);
            const u16* src = xb + ((size_t)(R0 + r) * PW_ + (C0 + c)) * CIN_ + ci0 + q * 8;
            GLOAD_LDS16(src, &lin[(size_t)(rd * 512 + wv * 64) * 8]);
        }
        // ---- stage weights tap 0 into buf 0 ----
        {
            const u16* srcA = wT + (size_t)0 * CIN_ * CIN_ + woff + ci0;
            GLOAD_LDS16(srcA, &lwt[0][(size_t)(wv * 64) * 8]);
        }
        __syncthreads();

#pragma unroll
        for (int tap = 0; tap < 9; ++tap) {
            const int kr = tap / 3, kc = tap - 3 * (tap / 3);
            // prefetch next tap's weights into the other buffer
            if (tap < 8) {
                const u16* srcA = wT + (size_t)(tap + 1) * CIN_ * CIN_ + woff + ci0;
                GLOAD_LDS16(srcA, &lwt[(tap + 1) & 1][(size_t)(wv * 64) * 8]);
            }
            // A-frags: co = wm*64 + mf*16 + lm, ci-sub hi
            bf16x8 av[4];
#pragma unroll
            for (int mf = 0; mf < 4; ++mf) {
                int co = wm * 64 + mf * 16 + lm;
                int unit = co * 4 + (hi ^ ((co >> 1) & 3));
                av[mf] = *(const bf16x8*)&lwt[tap & 1][(size_t)unit * 8];
            }
            // B-frags: row nf+kr, col wn*16+lm+kc
#pragma unroll
            for (int nf = 0; nf < 4; ++nf) {
                int c = wn * 16 + lm + kc;
                int rc = (nf + kr) * 66 + c;
                int unit = rc * 4 + (hi ^ ((c >> 1) & 3));
                bf16x8 bv = *(const bf16x8*)&lin[(size_t)unit * 8];
#pragma unroll
                for (int mf = 0; mf < 4; ++mf)
                    acc[mf][nf] = __builtin_amdgcn_mfma_f32_16x16x32_bf16(
                        av[mf], bv, acc[mf][nf], 0, 0, 0);
            }
            __syncthreads();
        }
    }

    // epilogue: BN + ReLU, pack 4 co (bf16) per lane, store 8B
#pragma unroll
    for (int mf = 0; mf < 4; ++mf) {
        int co0 = wm * 64 + mf * 16 + hi * 4;
        float4 g4 = *(const float4*)(gg + co0);
        float4 b4 = *(const float4*)(bbn + co0);
        float4 m4 = *(const float4*)(mmn + co0);
        float4 v4 = *(const float4*)(vvn + co0);
        float sc0 = g4.x / sqrtf(v4.x + 1e-5f), sh0 = b4.x - m4.x * sc0;
        float sc1 = g4.y / sqrtf(v4.y + 1e-5f), sh1 = b4.y - m4.y * sc1;
        float sc2 = g4.z / sqrtf(v4.z + 1e-5f), sh2 = b4.z - m4.z * sc2;
        float sc3 = g4.w / sqrtf(v4.w + 1e-5f), sh3 = b4.w - m4.w * sc3;
#pragma unroll
        for (int nf = 0; nf < 4; ++nf) {
            f32x4 A = acc[mf][nf];
            float y0 = fmaxf(fmaf(A[0], sc0, sh0), 0.f);
            float y1 = fmaxf(fmaf(A[1], sc1, sh1), 0.f);
            float y2 = fmaxf(fmaf(A[2], sc2, sh2), 0.f);
            float y3 = fmaxf(fmaf(A[3], sc3, sh3), 0.f);
            unsigned p0 = (unsigned)f2bf(y0) | ((unsigned)f2bf(y1) << 16);
            unsigned p1 = (unsigned)f2bf(y2) | ((unsigned)f2bf(y3) << 16);
            u16* op = yT + (size_t)b * PW_ * PW_ * CIN_ +
                      ((size_t)(R0 + nf + 1) * PW_ + (C0 + wn * 16 + lm + 1)) * CIN_ + co0;
            *(uint2*)op = make_uint2(p0, p1);
        }
    }
}

// ---------------------------------------------------------------------------
// head: 11 outputs (2 hm + 9 reg) via MFMA, co padded to 16. (validated r3)
// ---------------------------------------------------------------------------
__global__ __launch_bounds__(256) void k_head_mfma(
    const u16* __restrict__ f2T, const u16* __restrict__ wTh,
    const float* __restrict__ hb, const float* __restrict__ rb,
    float* __restrict__ out)
{
    int wave = threadIdx.x >> 6;
    int lane = threadIdx.x & 63;
    int lm = lane & 15, hi = lane >> 4;
    int C0 = min((int)blockIdx.x * 16, 164);
    int R0 = min((int)blockIdx.y * 16, 164);
    int b  = blockIdx.z;
    int RW = R0 + wave * 4;
    const u16* xb = f2T + (size_t)b * PW_ * PW_ * CIN_;

    f32x4 acc[4];
#pragma unroll
    for (int i = 0; i < 4; ++i) acc[i] = (f32x4){0.f, 0.f, 0.f, 0.f};

    const u16* aB = wTh + (size_t)lm * CIN_ + hi * 8;
    const u16* bB = xb + ((size_t)RW * PW_ + C0 + lm) * CIN_ + hi * 8;

    for (int ci0 = 0; ci0 < CIN_; ci0 += 32) {
#pragma unroll
        for (int tap = 0; tap < 9; ++tap) {
            const int kr = tap / 3, kc = tap - 3 * (tap / 3);
            bf16x8 av = *(const bf16x8*)(aB + tap * (16 * CIN_) + ci0);
            bf16x8 bv[4];
#pragma unroll
            for (int nf = 0; nf < 4; ++nf)
                bv[nf] = *(const bf16x8*)(bB + ((kr + nf) * PW_ + kc) * CIN_ + ci0);
#pragma unroll
            for (int nf = 0; nf < 4; ++nf)
                acc[nf] = __builtin_amdgcn_mfma_f32_16x16x32_bf16(av, bv[nf], acc[nf], 0, 0, 0);
        }
    }

#pragma unroll
    for (int nf = 0; nf < 4; ++nf) {
        int row = RW + nf, col = C0 + lm;
        f32x4 A = acc[nf];
#pragma unroll
        for (int r = 0; r < 4; ++r) {
            int co = hi * 4 + r;
            float v = A[r];
            if (co < 2)
                out[HM_OFF + ((size_t)(b * 2 + co)) * HW_ + row * FW_ + col] = v + hb[co];
            else if (co < 11)
                out[REG_OFF + ((size_t)(b * 9 + co - 2)) * HW_ + row * FW_ + col] = v + rb[co - 2];
        }
    }
}

// ---------------------------------------------------------------------------
// targets (unchanged — validated rounds 1-3)
// ---------------------------------------------------------------------------
__global__ void k_zero_heat(float* __restrict__ out)
{
    int i = blockIdx.x * 256 + threadIdx.x;
    if (i < BB_ * 2 * HW_) out[HEAT_OFF + i] = 0.f;
}

__global__ void k_objects(const float* __restrict__ gt, float* __restrict__ out)
{
    int ob = blockIdx.x;
    int b = ob / MM_, m = ob % MM_;
    const float* gp = gt + (size_t)ob * 8;
    float x = gp[0], y = gp[1], z = gp[2];
    float dx = gp[3], dy = gp[4], dz = gp[5], ry = gp[6];
    int cls = (int)gp[7];

    float coord_x = fminf(fmaxf((x + 54.f) / 0.075f / 8.f, 0.f), 179.5f);
    float coord_y = fminf(fmaxf((y + 54.f) / 0.075f / 8.f, 0.f), 179.5f);
    int cxi = (int)coord_x, cyi = (int)coord_y;
    float dxp = dx / 0.075f / 8.f;
    float dyp = dy / 0.075f / 8.f;

    float hgt = dxp, wid = dyp, mo = 0.1f;
    float b1 = hgt + wid, c1 = wid * hgt * (1.f - mo) / (1.f + mo);
    float r1 = (b1 + sqrtf(fmaxf(b1 * b1 - 4.f * c1, 0.f))) * 0.5f;
    float b2 = 2.f * (hgt + wid), c2 = (1.f - mo) * wid * hgt;
    float r2 = (b2 + sqrtf(fmaxf(b2 * b2 - 16.f * c2, 0.f))) * 0.5f;
    float a3 = 4.f * mo, b3 = -2.f * mo * (hgt + wid), c3 = (mo - 1.f) * wid * hgt;
    float r3 = (b3 + sqrtf(fmaxf(b3 * b3 - 4.f * a3 * c3, 0.f))) / (2.f * a3);
    int radius = max((int)fminf(fminf(r1, r2), r3), 2);

    bool valid = (dxp > 0.f) && (dyp > 0.f);
    bool pos = valid && (cls >= 1);

    if (threadIdx.x == 0) {
        float m0 = valid ? (cls >= 1 ? 1.f : -1.f) : 0.f;
        bool w_cond = (0.075f * 8.f) > dy / 4.f;
        bool l_cond = (0.075f * 8.f) > dx / 4.f;
        bool s1 = valid && !w_cond && (cxi - 1 >= 0);
        bool s2 = valid && !w_cond && (cxi + 1 < FW_);
        bool s3 = valid && !l_cond && (cyi - 1 >= 0);
        bool s4 = valid && !l_cond && (cyi + 1 < FH_);
        int base_ind = cyi * FW_ + cxi;

        float* indp = out + IND_OFF + (size_t)b * MM_ * 5 + m * 5;
        float* mskp = out + MSK_OFF + (size_t)b * MM_ * 5 + m * 5;
        indp[0] = valid ? (float)base_ind : 0.f;
        indp[1] = s1 ? (float)(base_ind - 1) : 0.f;
        indp[2] = s2 ? (float)(base_ind + 1) : 0.f;
        indp[3] = s3 ? (float)(base_ind - FW_) : 0.f;
        indp[4] = s4 ? (float)(base_ind + FW_) : 0.f;
        mskp[0] = m0;
        mskp[1] = s1 ? m0 : 0.f;
        mskp[2] = s2 ? m0 : 0.f;
        mskp[3] = s3 ? m0 : 0.f;
        mskp[4] = s4 ? m0 : 0.f;

        float offx = coord_x - (float)cxi;
        float offy = coord_y - (float)cyi;
        float bse[8] = { offx, offy, z,
                         logf(fmaxf(dx, 1e-8f)), logf(fmaxf(dy, 1e-8f)),
                         logf(fmaxf(dz, 1e-8f)), cosf(ry), sinf(ry) };
        float vm = valid ? 1.f : 0.f;
        float* rbp = out + RB_OFF + ((size_t)b * MM_ + m) * 5 * 8;
#pragma unroll
        for (int s = 0; s < 5; ++s) {
            float t0 = bse[0], t1 = bse[1];
            if (s == 1) t0 += s1 ? 1.f : 0.f;
            if (s == 2) t0 -= s2 ? 1.f : 0.f;
            if (s == 3) t1 += s3 ? 1.f : 0.f;
            if (s == 4) t1 -= s4 ? 1.f : 0.f;
            rbp[s * 8 + 0] = t0 * vm;
            rbp[s * 8 + 1] = t1 * vm;
#pragma unroll
            for (int k = 2; k < 8; ++k) rbp[s * 8 + k] = bse[k] * vm;
        }
    }

    if (pos) {
        float sigma = (2.f * (float)radius + 1.f) / 6.f;
        float inv2s2 = 1.f / (2.f * sigma * sigma);
        int x0 = max(cxi - radius, 0), x1 = min(cxi + radius, FW_ - 1);
        int y0 = max(cyi - radius, 0), y1 = min(cyi + radius, FH_ - 1);
        int wdt = x1 - x0 + 1, tot = wdt * (y1 - y0 + 1);
        float* hp = out + HEAT_OFF + (size_t)(b * 2 + (cls - 1)) * HW_;
        for (int i = threadIdx.x; i < tot; i += blockDim.x) {
            int yy = y0 + i / wdt, xx = x0 + i % wdt;
            float ddy = (float)(yy - cyi), ddx = (float)(xx - cxi);
            float gvl = expf(-(ddy * ddy + ddx * ddx) * inv2s2);
            atomicMax((int*)(hp + yy * FW_ + xx), __float_as_int(gvl));
        }
    }
}

__global__ void k_hm_mask(float* __restrict__ out)
{
    int i = blockIdx.x * 256 + threadIdx.x;
    if (i < BB_ * 2 * HW_) {
        float v = out[HEAT_OFF + i];
        out[HMM_OFF + i] = v > 0.f ? 1.f : 0.f;
    }
}

// ---------------------------------------------------------------------------
extern "C" void kernel_launch(void* const* d_in, const int* in_sizes, int n_in,
                              void* d_out, int out_size, void* d_ws, size_t ws_size,
                              hipStream_t stream)
{
    const float* x  = (const float*)d_in[0];
    const float* gt = (const float*)d_in[1];
    const float* w1 = (const float*)d_in[2];
    const float* g1 = (const float*)d_in[3];
    const float* b1 = (const float*)d_in[4];
    const float* m1 = (const float*)d_in[5];
    const float* v1 = (const float*)d_in[6];
    const float* w2 = (const float*)d_in[7];
    const float* g2 = (const float*)d_in[8];
    const float* b2 = (const float*)d_in[9];
    const float* m2 = (const float*)d_in[10];
    const float* v2 = (const float*)d_in[11];
    const float* hw = (const float*)d_in[12];
    const float* hb = (const float*)d_in[13];
    const float* rw = (const float*)d_in[14];
    const float* rb = (const float*)d_in[15];
    float* out = (float*)d_out;

    u16* ws  = (u16*)d_ws;
    u16* xT  = ws;                       // padded channel-last bf16 buffers
    u16* f1T = ws + PADE;
    u16* f2T = ws + 2 * PADE;
    u16* wT1 = ws + 3 * PADE;            // 9*128*128
    u16* wT2 = wT1 + 9 * CIN_ * CIN_;
    u16* wTh = wT2 + 9 * CIN_ * CIN_;    // 9*16*128

    k_zero_borders<<<(3 * BB_ * PW_ * PW_ + 255) / 256, 256, 0, stream>>>(ws);
    k_prep_xT<<<dim3(180, BB_), 256, 0, stream>>>(x, xT);
    k_prep_wT<<<(9 * CIN_ * CIN_ + 255) / 256, 256, 0, stream>>>(w1, wT1);
    k_prep_wT<<<(9 * CIN_ * CIN_ + 255) / 256, 256, 0, stream>>>(w2, wT2);
    k_prep_wTh<<<(9 * 16 * CIN_ + 255) / 256, 256, 0, stream>>>(hw, rw, wTh);

    dim3 cg(3, 45, BB_);
    k_conv_mfma2<<<cg, 512, 0, stream>>>(xT,  wT1, g1, b1, m1, v1, f1T);
    k_conv_mfma2<<<cg, 512, 0, stream>>>(f1T, wT2, g2, b2, m2, v2, f2T);

    dim3 hg(12, 12, BB_);
    k_head_mfma<<<hg, 256, 0, stream>>>(f2T, wTh, hb, rb, out);

    k_zero_heat<<<(BB_ * 2 * HW_ + 255) / 256, 256, 0, stream>>>(out);
    k_objects<<<BB_ * MM_, 64, 0, stream>>>(gt, out);
    k_hm_mask<<<(BB_ * 2 * HW_ + 255) / 256, 256, 0, stream>>>(out);
}

// Round 5
// 158.306 us; speedup vs baseline: 28.8603x; 1.3104x over previous
//
#include <hip/hip_runtime.h>
#include <math.h>

typedef unsigned short u16;
typedef short bf16x8 __attribute__((ext_vector_type(8)));
typedef float f32x4 __attribute__((ext_vector_type(4)));

#define FW_ 180
#define FH_ 180
#define HW_ (FW_*FH_)
#define CIN_ 128
#define BB_ 4
#define MM_ 500
#define PW_ 182
#define PADE ((size_t)BB_*PW_*PW_*CIN_)

// d_out segment offsets (floats), in reference return order
#define HM_OFF   0
#define REG_OFF  (BB_*2*HW_)
#define HEAT_OFF (REG_OFF + BB_*9*HW_)
#define RB_OFF   (HEAT_OFF + BB_*2*HW_)
#define IND_OFF  (RB_OFF + BB_*MM_*5*8)
#define MSK_OFF  (IND_OFF + BB_*MM_*5)
#define HMM_OFF  (MSK_OFF + BB_*MM_*5)

__device__ inline u16 f2bf(float f) {
    unsigned u = __float_as_uint(f);
    u += 0x7FFFu + ((u >> 16) & 1u);           // RNE
    return (u16)(u >> 16);
}

#define GLOAD_LDS16(gsrc, ldst) \
    __builtin_amdgcn_global_load_lds( \
        (const __attribute__((address_space(1))) unsigned*)(gsrc), \
        (__attribute__((address_space(3))) unsigned*)(ldst), 16, 0, 0)

// ---------------------------------------------------------------------------
// init: zero 1-px borders of the 3 padded feature buffers + zero heatmap out
// ---------------------------------------------------------------------------
__global__ void k_init(u16* __restrict__ ws, float* __restrict__ out)
{
    int idx = blockIdx.x * 256 + threadIdx.x;
    const int n1 = 3 * BB_ * PW_ * PW_;
    if (idx < n1) {
        int buf = idx / (BB_ * PW_ * PW_);
        int rem = idx % (BB_ * PW_ * PW_);
        int p = rem % (PW_ * PW_);
        int r = p / PW_, c = p % PW_;
        if (r > 0 && r < PW_ - 1 && c > 0 && c < PW_ - 1) return;
        u16* base = ws + (size_t)buf * PADE + (size_t)rem * CIN_;
#pragma unroll
        for (int i = 0; i < 16; ++i) ((uint4*)base)[i] = make_uint4(0, 0, 0, 0);
    } else {
        int i = idx - n1;
        if (i < BB_ * 2 * HW_) out[HEAT_OFF + i] = 0.f;
    }
}

// ---------------------------------------------------------------------------
// x (f32 NCHW) -> xT (bf16 [b][row+1][col+1][ci] padded), vectorized
// ---------------------------------------------------------------------------
__global__ __launch_bounds__(256) void k_prep_xT(const float* __restrict__ in,
                                                 u16* __restrict__ xT)
{
    __shared__ unsigned lt32[180 * 65];        // [col][ci2] packed 2xbf16
    int tid = threadIdx.x;
    int row = blockIdx.x, b = blockIdx.y;
    const float* inr = in + ((size_t)b * CIN_ * FH_ + row) * FW_;
    for (int i = tid; i < 64 * 45; i += 256) {
        int ci2 = i / 45, c4 = i - 45 * ci2;
        const float* p0 = inr + (size_t)(2 * ci2) * HW_ + c4 * 4;
        float4 a = *(const float4*)p0;
        float4 bq = *(const float4*)(p0 + HW_);
        lt32[(c4 * 4 + 0) * 65 + ci2] = (unsigned)f2bf(a.x) | ((unsigned)f2bf(bq.x) << 16);
        lt32[(c4 * 4 + 1) * 65 + ci2] = (unsigned)f2bf(a.y) | ((unsigned)f2bf(bq.y) << 16);
        lt32[(c4 * 4 + 2) * 65 + ci2] = (unsigned)f2bf(a.z) | ((unsigned)f2bf(bq.z) << 16);
        lt32[(c4 * 4 + 3) * 65 + ci2] = (unsigned)f2bf(a.w) | ((unsigned)f2bf(bq.w) << 16);
    }
    __syncthreads();
    unsigned* dst = (unsigned*)(xT + ((size_t)b * PW_ * PW_ + (size_t)(row + 1) * PW_ + 1) * CIN_);
    for (int idx = tid; idx < 180 * 64; idx += 256) {
        int col = idx >> 6, c2 = idx & 63;
        dst[col * 64 + c2] = lt32[col * 65 + c2];
    }
}

// ---------------------------------------------------------------------------
// all weight transposes in one kernel:
//   wT1/wT2: [tap][co][ci] bf16 ; wTh: [tap][co16][ci] bf16
// ---------------------------------------------------------------------------
__global__ void k_prep_w(const float* __restrict__ w1, const float* __restrict__ w2,
                         const float* __restrict__ hw, const float* __restrict__ rw,
                         u16* __restrict__ wT1, u16* __restrict__ wT2,
                         u16* __restrict__ wTh)
{
    int i = blockIdx.x * 256 + threadIdx.x;
    const int NW = 9 * CIN_ * CIN_;
    if (i < NW) {
        int tap = i / (CIN_ * CIN_);
        int r = i % (CIN_ * CIN_);
        int co = r >> 7, ci = r & 127;
        wT1[i] = f2bf(w1[((size_t)co * CIN_ + ci) * 9 + tap]);
    } else if (i < 2 * NW) {
        int j = i - NW;
        int tap = j / (CIN_ * CIN_);
        int r = j % (CIN_ * CIN_);
        int co = r >> 7, ci = r & 127;
        wT2[j] = f2bf(w2[((size_t)co * CIN_ + ci) * 9 + tap]);
    } else {
        int j = i - 2 * NW;
        if (j >= 9 * 16 * CIN_) return;
        int tap = j / (16 * CIN_);
        int r = j % (16 * CIN_);
        int co = r >> 7, ci = r & 127;
        float v = 0.f;
        if (co < 2)       v = hw[((size_t)co * CIN_ + ci) * 9 + tap];
        else if (co < 11) v = rw[((size_t)(co - 2) * CIN_ + ci) * 9 + tap];
        wTh[j] = f2bf(v);
    }
}

// ---------------------------------------------------------------------------
// conv 3x3 SAME 128->128 + BN + ReLU. Block: 4 waves, out tile
// 64co x 4rows x 64cols. ONE barrier pair per 32-ci chunk: stage input halo
// (6x66x32, 1600 units) + ALL 9 taps' weights (2304 units) then 144 MFMA
// per wave straight-line. XOR-swizzled LDS units, sources pre-swizzled.
// ---------------------------------------------------------------------------
__global__ __launch_bounds__(256) void k_conv_v5(
    const u16* __restrict__ xT, const u16* __restrict__ wT,
    const float* __restrict__ gg, const float* __restrict__ bbn,
    const float* __restrict__ mmn, const float* __restrict__ vvn,
    u16* __restrict__ yT)
{
    __shared__ u16 lin[1600 * 8];        // 25.6 KB input halo chunk
    __shared__ u16 lwt[2304 * 8];        // 36.9 KB weights, all taps

    int tid  = threadIdx.x;
    int wv   = tid >> 6, lane = tid & 63;
    int lm   = lane & 15, hi = lane >> 4;
    int csp  = blockIdx.x % 3, cog = blockIdx.x / 3;
    int C0   = (csp == 2) ? 116 : csp * 64;
    int cob  = cog * 64;
    int R0   = blockIdx.y * 4;
    int b    = blockIdx.z;
    const u16* xb = xT + (size_t)b * PW_ * PW_ * CIN_;

    f32x4 acc[4][4];
#pragma unroll
    for (int i = 0; i < 4; ++i)
#pragma unroll
        for (int j = 0; j < 4; ++j) acc[i][j] = (f32x4){0.f, 0.f, 0.f, 0.f};

    // per-thread weight-stage source offsets (9 rounds)
    const int wco = (tid & 255) >> 2;
    const int wq  = (tid & 3) ^ ((wco >> 1) & 3);

#pragma unroll 1
    for (int ch = 0; ch < 4; ++ch) {
        int ci0 = ch * 32;
        __syncthreads();
        // ---- stage input: rounds 0..5 all waves, round 6 wave 0 only ----
#pragma unroll
        for (int rd = 0; rd < 6; ++rd) {
            int o = rd * 256 + tid;
            int rc = o >> 2;
            int r = rc / 66, c = rc - 66 * r;
            int q = (o & 3) ^ ((c >> 1) & 3);
            const u16* src = xb + ((size_t)(R0 + r) * PW_ + (C0 + c)) * CIN_ + ci0 + q * 8;
            GLOAD_LDS16(src, &lin[(size_t)(rd * 256 + wv * 64) * 8]);
        }
        if (wv == 0) {
            int o = 1536 + lane;
            int rc = o >> 2;
            int r = rc / 66, c = rc - 66 * r;
            if (o >= 1584) { r = 5; c = 65; }
            int q = (o & 3) ^ ((c >> 1) & 3);
            const u16* src = xb + ((size_t)(R0 + r) * PW_ + (C0 + c)) * CIN_ + ci0 + q * 8;
            GLOAD_LDS16(src, &lin[(size_t)1536 * 8]);
        }
        // ---- stage weights: 9 rounds (tap = round) ----
#pragma unroll
        for (int tap = 0; tap < 9; ++tap) {
            const u16* src = wT + (size_t)tap * CIN_ * CIN_ + (size_t)(cob + wco) * CIN_ + ci0 + wq * 8;
            GLOAD_LDS16(src, &lwt[(size_t)(tap * 256 + wv * 64) * 8]);
        }
        __syncthreads();

        // ---- compute: 9 taps x 16 MFMA, no barriers ----
#pragma unroll
        for (int tap = 0; tap < 9; ++tap) {
            const int kr = tap / 3, kc = tap - 3 * (tap / 3);
            bf16x8 av[4];
#pragma unroll
            for (int mf = 0; mf < 4; ++mf) {
                int col = mf * 16 + lm;
                int unit = tap * 256 + col * 4 + (hi ^ ((col >> 1) & 3));
                av[mf] = *(const bf16x8*)&lwt[(size_t)unit * 8];
            }
#pragma unroll
            for (int nf = 0; nf < 4; ++nf) {
                int c = wv * 16 + lm + kc;
                int rc = (nf + kr) * 66 + c;
                int unit = rc * 4 + (hi ^ ((c >> 1) & 3));
                bf16x8 bv = *(const bf16x8*)&lin[(size_t)unit * 8];
#pragma unroll
                for (int mf = 0; mf < 4; ++mf)
                    acc[mf][nf] = __builtin_amdgcn_mfma_f32_16x16x32_bf16(
                        av[mf], bv, acc[mf][nf], 0, 0, 0);
            }
        }
    }

    // epilogue: BN + ReLU, pack 4 co bf16 per lane, 8B store
#pragma unroll
    for (int mf = 0; mf < 4; ++mf) {
        int co0 = cob + mf * 16 + hi * 4;
        float4 g4 = *(const float4*)(gg + co0);
        float4 b4 = *(const float4*)(bbn + co0);
        float4 m4 = *(const float4*)(mmn + co0);
        float4 v4 = *(const float4*)(vvn + co0);
        float sc0 = g4.x / sqrtf(v4.x + 1e-5f), sh0 = b4.x - m4.x * sc0;
        float sc1 = g4.y / sqrtf(v4.y + 1e-5f), sh1 = b4.y - m4.y * sc1;
        float sc2 = g4.z / sqrtf(v4.z + 1e-5f), sh2 = b4.z - m4.z * sc2;
        float sc3 = g4.w / sqrtf(v4.w + 1e-5f), sh3 = b4.w - m4.w * sc3;
#pragma unroll
        for (int nf = 0; nf < 4; ++nf) {
            f32x4 A = acc[mf][nf];
            float y0 = fmaxf(fmaf(A[0], sc0, sh0), 0.f);
            float y1 = fmaxf(fmaf(A[1], sc1, sh1), 0.f);
            float y2 = fmaxf(fmaf(A[2], sc2, sh2), 0.f);
            float y3 = fmaxf(fmaf(A[3], sc3, sh3), 0.f);
            unsigned p0 = (unsigned)f2bf(y0) | ((unsigned)f2bf(y1) << 16);
            unsigned p1 = (unsigned)f2bf(y2) | ((unsigned)f2bf(y3) << 16);
            u16* op = yT + (size_t)b * PW_ * PW_ * CIN_ +
                      ((size_t)(R0 + nf + 1) * PW_ + (C0 + wv * 16 + lm + 1)) * CIN_ + co0;
            *(uint2*)op = make_uint2(p0, p1);
        }
    }
}

// ---------------------------------------------------------------------------
// head: 2 hm + 9 reg channels (M=16 padded). Block: 4 waves, tile
// 16co x 4rows x 64cols. Weights (all taps, all ci: 36.9 KB) staged once;
// input halo chunk per 32-ci chunk.
// ---------------------------------------------------------------------------
__global__ __launch_bounds__(256) void k_head_v5(
    const u16* __restrict__ f2T, const u16* __restrict__ wTh,
    const float* __restrict__ hb, const float* __restrict__ rb,
    float* __restrict__ out)
{
    __shared__ u16 lin[1600 * 8];
    __shared__ u16 lwt[2304 * 8];        // [tap][co16][16 ci-units swz]

    int tid  = threadIdx.x;
    int wv   = tid >> 6, lane = tid & 63;
    int lm   = lane & 15, hi = lane >> 4;
    int csp  = blockIdx.x;
    int C0   = (csp == 2) ? 116 : csp * 64;
    int R0   = blockIdx.y * 4;
    int b    = blockIdx.z;
    const u16* xb = f2T + (size_t)b * PW_ * PW_ * CIN_;

    f32x4 acc[4];
#pragma unroll
    for (int i = 0; i < 4; ++i) acc[i] = (f32x4){0.f, 0.f, 0.f, 0.f};

    // stage all head weights once: 2304 units, 9 rounds
#pragma unroll
    for (int rd = 0; rd < 9; ++rd) {
        int o = rd * 256 + tid;
        int tap = o >> 8, rest = o & 255;
        int co = rest >> 4, u8s = rest & 15;
        const u16* src = wTh + (size_t)tap * 16 * CIN_ + co * CIN_ + ((u8s ^ (co & 7)) * 8);
        GLOAD_LDS16(src, &lwt[(size_t)(rd * 256 + wv * 64) * 8]);
    }

#pragma unroll 1
    for (int ch = 0; ch < 4; ++ch) {
        int ci0 = ch * 32;
        __syncthreads();
#pragma unroll
        for (int rd = 0; rd < 6; ++rd) {
            int o = rd * 256 + tid;
            int rc = o >> 2;
            int r = rc / 66, c = rc - 66 * r;
            int q = (o & 3) ^ ((c >> 1) & 3);
            const u16* src = xb + ((size_t)(R0 + r) * PW_ + (C0 + c)) * CIN_ + ci0 + q * 8;
            GLOAD_LDS16(src, &lin[(size_t)(rd * 256 + wv * 64) * 8]);
        }
        if (wv == 0) {
            int o = 1536 + lane;
            int rc = o >> 2;
            int r = rc / 66, c = rc - 66 * r;
            if (o >= 1584) { r = 5; c = 65; }
            int q = (o & 3) ^ ((c >> 1) & 3);
            const u16* src = xb + ((size_t)(R0 + r) * PW_ + (C0 + c)) * CIN_ + ci0 + q * 8;
            GLOAD_LDS16(src, &lin[(size_t)1536 * 8]);
        }
        __syncthreads();

#pragma unroll
        for (int tap = 0; tap < 9; ++tap) {
            const int kr = tap / 3, kc = tap - 3 * (tap / 3);
            int u8 = (ch * 4 + hi) ^ (lm & 7);
            bf16x8 av = *(const bf16x8*)&lwt[(size_t)(tap * 256 + lm * 16 + u8) * 8];
#pragma unroll
            for (int nf = 0; nf < 4; ++nf) {
                int c = wv * 16 + lm + kc;
                int rc = (nf + kr) * 66 + c;
                int unit = rc * 4 + (hi ^ ((c >> 1) & 3));
                bf16x8 bv = *(const bf16x8*)&lin[(size_t)unit * 8];
                acc[nf] = __builtin_amdgcn_mfma_f32_16x16x32_bf16(av, bv, acc[nf], 0, 0, 0);
            }
        }
    }

#pragma unroll
    for (int nf = 0; nf < 4; ++nf) {
        int row = R0 + nf, col = C0 + wv * 16 + lm;
        f32x4 A = acc[nf];
#pragma unroll
        for (int r = 0; r < 4; ++r) {
            int co = hi * 4 + r;
            float v = A[r];
            if (co < 2)
                out[HM_OFF + ((size_t)(b * 2 + co)) * HW_ + (size_t)row * FW_ + col] = v + hb[co];
            else if (co < 11)
                out[REG_OFF + ((size_t)(b * 9 + co - 2)) * HW_ + (size_t)row * FW_ + col] = v + rb[co - 2];
        }
    }
}

// ---------------------------------------------------------------------------
// targets (unchanged — validated rounds 1-4)
// ---------------------------------------------------------------------------
__global__ void k_objects(const float* __restrict__ gt, float* __restrict__ out)
{
    int ob = blockIdx.x;
    int b = ob / MM_, m = ob % MM_;
    const float* gp = gt + (size_t)ob * 8;
    float x = gp[0], y = gp[1], z = gp[2];
    float dx = gp[3], dy = gp[4], dz = gp[5], ry = gp[6];
    int cls = (int)gp[7];

    float coord_x = fminf(fmaxf((x + 54.f) / 0.075f / 8.f, 0.f), 179.5f);
    float coord_y = fminf(fmaxf((y + 54.f) / 0.075f / 8.f, 0.f), 179.5f);
    int cxi = (int)coord_x, cyi = (int)coord_y;
    float dxp = dx / 0.075f / 8.f;
    float dyp = dy / 0.075f / 8.f;

    float hgt = dxp, wid = dyp, mo = 0.1f;
    float b1 = hgt + wid, c1 = wid * hgt * (1.f - mo) / (1.f + mo);
    float r1 = (b1 + sqrtf(fmaxf(b1 * b1 - 4.f * c1, 0.f))) * 0.5f;
    float b2 = 2.f * (hgt + wid), c2 = (1.f - mo) * wid * hgt;
    float r2 = (b2 + sqrtf(fmaxf(b2 * b2 - 16.f * c2, 0.f))) * 0.5f;
    float a3 = 4.f * mo, b3 = -2.f * mo * (hgt + wid), c3 = (mo - 1.f) * wid * hgt;
    float r3 = (b3 + sqrtf(fmaxf(b3 * b3 - 4.f * a3 * c3, 0.f))) / (2.f * a3);
    int radius = max((int)fminf(fminf(r1, r2), r3), 2);

    bool valid = (dxp > 0.f) && (dyp > 0.f);
    bool pos = valid && (cls >= 1);

    if (threadIdx.x == 0) {
        float m0 = valid ? (cls >= 1 ? 1.f : -1.f) : 0.f;
        bool w_cond = (0.075f * 8.f) > dy / 4.f;
        bool l_cond = (0.075f * 8.f) > dx / 4.f;
        bool s1 = valid && !w_cond && (cxi - 1 >= 0);
        bool s2 = valid && !w_cond && (cxi + 1 < FW_);
        bool s3 = valid && !l_cond && (cyi - 1 >= 0);
        bool s4 = valid && !l_cond && (cyi + 1 < FH_);
        int base_ind = cyi * FW_ + cxi;

        float* indp = out + IND_OFF + (size_t)b * MM_ * 5 + m * 5;
        float* mskp = out + MSK_OFF + (size_t)b * MM_ * 5 + m * 5;
        indp[0] = valid ? (float)base_ind : 0.f;
        indp[1] = s1 ? (float)(base_ind - 1) : 0.f;
        indp[2] = s2 ? (float)(base_ind + 1) : 0.f;
        indp[3] = s3 ? (float)(base_ind - FW_) : 0.f;
        indp[4] = s4 ? (float)(base_ind + FW_) : 0.f;
        mskp[0] = m0;
        mskp[1] = s1 ? m0 : 0.f;
        mskp[2] = s2 ? m0 : 0.f;
        mskp[3] = s3 ? m0 : 0.f;
        mskp[4] = s4 ? m0 : 0.f;

        float offx = coord_x - (float)cxi;
        float offy = coord_y - (float)cyi;
        float bse[8] = { offx, offy, z,
                         logf(fmaxf(dx, 1e-8f)), logf(fmaxf(dy, 1e-8f)),
                         logf(fmaxf(dz, 1e-8f)), cosf(ry), sinf(ry) };
        float vm = valid ? 1.f : 0.f;
        float* rbp = out + RB_OFF + ((size_t)b * MM_ + m) * 5 * 8;
#pragma unroll
        for (int s = 0; s < 5; ++s) {
            float t0 = bse[0], t1 = bse[1];
            if (s == 1) t0 += s1 ? 1.f : 0.f;
            if (s == 2) t0 -= s2 ? 1.f : 0.f;
            if (s == 3) t1 += s3 ? 1.f : 0.f;
            if (s == 4) t1 -= s4 ? 1.f : 0.f;
            rbp[s * 8 + 0] = t0 * vm;
            rbp[s * 8 + 1] = t1 * vm;
#pragma unroll
            for (int k = 2; k < 8; ++k) rbp[s * 8 + k] = bse[k] * vm;
        }
    }

    if (pos) {
        float sigma = (2.f * (float)radius + 1.f) / 6.f;
        float inv2s2 = 1.f / (2.f * sigma * sigma);
        int x0 = max(cxi - radius, 0), x1 = min(cxi + radius, FW_ - 1);
        int y0 = max(cyi - radius, 0), y1 = min(cyi + radius, FH_ - 1);
        int wdt = x1 - x0 + 1, tot = wdt * (y1 - y0 + 1);
        float* hp = out + HEAT_OFF + (size_t)(b * 2 + (cls - 1)) * HW_;
        for (int i = threadIdx.x; i < tot; i += blockDim.x) {
            int yy = y0 + i / wdt, xx = x0 + i % wdt;
            float ddy = (float)(yy - cyi), ddx = (float)(xx - cxi);
            float gvl = expf(-(ddy * ddy + ddx * ddx) * inv2s2);
            atomicMax((int*)(hp + yy * FW_ + xx), __float_as_int(gvl));
        }
    }
}

__global__ void k_hm_mask(float* __restrict__ out)
{
    int i = blockIdx.x * 256 + threadIdx.x;
    if (i < BB_ * 2 * HW_) {
        float v = out[HEAT_OFF + i];
        out[HMM_OFF + i] = v > 0.f ? 1.f : 0.f;
    }
}

// ---------------------------------------------------------------------------
extern "C" void kernel_launch(void* const* d_in, const int* in_sizes, int n_in,
                              void* d_out, int out_size, void* d_ws, size_t ws_size,
                              hipStream_t stream)
{
    const float* x  = (const float*)d_in[0];
    const float* gt = (const float*)d_in[1];
    const float* w1 = (const float*)d_in[2];
    const float* g1 = (const float*)d_in[3];
    const float* b1 = (const float*)d_in[4];
    const float* m1 = (const float*)d_in[5];
    const float* v1 = (const float*)d_in[6];
    const float* w2 = (const float*)d_in[7];
    const float* g2 = (const float*)d_in[8];
    const float* b2 = (const float*)d_in[9];
    const float* m2 = (const float*)d_in[10];
    const float* v2 = (const float*)d_in[11];
    const float* hw = (const float*)d_in[12];
    const float* hb = (const float*)d_in[13];
    const float* rw = (const float*)d_in[14];
    const float* rb = (const float*)d_in[15];
    float* out = (float*)d_out;

    u16* ws  = (u16*)d_ws;
    u16* xT  = ws;
    u16* f1T = ws + PADE;
    u16* f2T = ws + 2 * PADE;
    u16* wT1 = ws + 3 * PADE;
    u16* wT2 = wT1 + 9 * CIN_ * CIN_;
    u16* wTh = wT2 + 9 * CIN_ * CIN_;

    const int NINIT = 3 * BB_ * PW_ * PW_ + BB_ * 2 * HW_;
    k_init<<<(NINIT + 255) / 256, 256, 0, stream>>>(ws, out);
    k_prep_xT<<<dim3(180, BB_), 256, 0, stream>>>(x, xT);
    const int NWALL = 2 * 9 * CIN_ * CIN_ + 9 * 16 * CIN_;
    k_prep_w<<<(NWALL + 255) / 256, 256, 0, stream>>>(w1, w2, hw, rw, wT1, wT2, wTh);

    dim3 cg(6, 45, BB_);
    k_conv_v5<<<cg, 256, 0, stream>>>(xT,  wT1, g1, b1, m1, v1, f1T);
    k_conv_v5<<<cg, 256, 0, stream>>>(f1T, wT2, g2, b2, m2, v2, f2T);

    dim3 hg(3, 45, BB_);
    k_head_v5<<<hg, 256, 0, stream>>>(f2T, wTh, hb, rb, out);

    k_objects<<<BB_ * MM_, 64, 0, stream>>>(gt, out);
    k_hm_mask<<<(BB_ * 2 * HW_ + 255) / 256, 256, 0, stream>>>(out);
}